// Round 15
// baseline (695.023 us; speedup 1.0000x reference)
//
#include <hip/hip_runtime.h>

#define BB 8
#define NP 4096    // NPTS == NQ
#define NN 1024
#define NE 8192
#define FF 256
#define TS 264
#define NSTEP 16
#define NSEG 64
#define SEGSZ 128  // NSEG*SEGSZ == NE
#define EMAX 1536  // per-block staged CSR records (mean ~288)

typedef float f32x4_t __attribute__((ext_vector_type(4)));
typedef __bf16 bf16x8_t __attribute__((ext_vector_type(8)));
typedef unsigned int u32x4_t __attribute__((ext_vector_type(4)));
typedef unsigned int u32x2_t __attribute__((ext_vector_type(2)));

// hardware RNE f32->bf16; bit-identical to SW round-to-nearest-even on normals
static __device__ __forceinline__ unsigned short f2bf(float f) {
  return __builtin_bit_cast(unsigned short, static_cast<__bf16>(f));
}
static __device__ __forceinline__ float ashf(unsigned short s) {
  union { unsigned u; float f; } t; t.u = (unsigned)s << 16; return t.f;
}
// split a,b into hi/lo bf16 pairs packed as u32
static __device__ __forceinline__ void split_pk(float a, float b, unsigned& h, unsigned& l) {
  unsigned short ha = f2bf(a), hb = f2bf(b);
  unsigned short la = f2bf(a - ashf(ha)), lb = f2bf(b - ashf(hb));
  h = (unsigned)ha | ((unsigned)hb << 16);
  l = (unsigned)la | ((unsigned)lb << 16);
}
static __device__ __forceinline__ f32x4_t mfma16(u32x4_t a, u32x4_t b, f32x4_t c) {
  return __builtin_amdgcn_mfma_f32_16x16x32_bf16(
      __builtin_bit_cast(bf16x8_t, a), __builtin_bit_cast(bf16x8_t, b), c, 0, 0, 0);
}
// 16B-entry XOR swizzle: spreads 64-byte fragment rows over all 32 LDS banks
static __device__ __forceinline__ int swz16(int e) { return e ^ ((e >> 3) & 7); }

// ---------------- graph preprocessing (segmented, deterministic) ----------------
__global__ __launch_bounds__(1024) void k_cnt(const int* __restrict__ dstA,
                                              int* __restrict__ cntg) {
  __shared__ int ds[SEGSZ];
  int seg = blockIdx.x, n = threadIdx.x;
  if (n < SEGSZ) ds[n] = dstA[seg * SEGSZ + n];
  __syncthreads();
  int c = 0;
  #pragma unroll 8
  for (int e = 0; e < SEGSZ; e++) c += (ds[e] == n) ? 1 : 0;
  cntg[seg * NN + n] = c;
}

__global__ __launch_bounds__(1024) void k_scan2(const int* __restrict__ cntg,
    float* __restrict__ dinv, int* __restrict__ csr_off) {
  __shared__ int s[NN];
  int n = threadIdx.x;
  int c = 1;
  for (int sg = 0; sg < NSEG; sg++) c += cntg[sg * NN + n];
  dinv[n] = rsqrtf((float)c);
  s[n] = c;
  __syncthreads();
  for (int st = 1; st < NN; st <<= 1) {
    int v = (n >= st) ? s[n - st] : 0;
    __syncthreads();
    s[n] += v;
    __syncthreads();
  }
  csr_off[n] = s[n] - c;
  if (n == NN - 1) csr_off[NN] = s[n];
}

__global__ __launch_bounds__(1024) void k_fill2(const int* __restrict__ srcA,
    const int* __restrict__ dstA, const float* __restrict__ dinv,
    const int* __restrict__ csr_off, const int* __restrict__ cntg,
    int* __restrict__ csr_src, float* __restrict__ csr_w) {
  int n = threadIdx.x;
  if (blockIdx.x == NSEG) {
    int pos = csr_off[n + 1] - 1;               // self loop last
    csr_src[pos] = n;
    csr_w[pos] = dinv[n] * dinv[n];
    return;
  }
  __shared__ int ds[SEGSZ], ss[SEGSZ];
  int seg = blockIdx.x;
  if (n < SEGSZ) { ds[n] = dstA[seg * SEGSZ + n]; ss[n] = srcA[seg * SEGSZ + n]; }
  __syncthreads();
  int base = csr_off[n];
  for (int s2 = 0; s2 < seg; s2++) base += cntg[s2 * NN + n];
  float dn = dinv[n];
  for (int e = 0; e < SEGSZ; e++) {
    if (ds[e] == n) {
      int sv = ss[e];
      csr_src[base] = sv;
      csr_w[base] = dinv[sv] * dn;
      base++;
    }
  }
}

// spos + sposW fused: one block per node n; spos sum recomputed redundantly per thread
__global__ __launch_bounds__(256) void k_posb(const float* __restrict__ npos,
    const int* __restrict__ csr_off, const int* __restrict__ csr_src,
    const float* __restrict__ csr_w, const float* __restrict__ Wg,
    const float* __restrict__ bg, float* __restrict__ sposW) {
  int n = blockIdx.x, f = threadIdx.x;
  float sx = 0.f, sy = 0.f;
  int e1 = csr_off[n + 1];
  for (int e = csr_off[n]; e < e1; e++) {
    float w = csr_w[e]; int s = csr_src[e];
    sx += w * npos[2 * s]; sy += w * npos[2 * s + 1];
  }
  sposW[(size_t)n * FF + f] = sx * Wg[f] + sy * Wg[FF + f] + bg[f];
}

// ---------------- softmax stats (inputs and queries in one launch) ----------------
__global__ __launch_bounds__(256) void k_stats(const float* __restrict__ inx,
    const float* __restrict__ qxy, const float* __restrict__ npos,
    float* __restrict__ mI, float* __restrict__ liI,
    float* __restrict__ mQ, float* __restrict__ liQ) {
  const float* xy = blockIdx.y ? qxy : inx;
  float* mOut = blockIdx.y ? mQ : mI;
  float* liOut = blockIdx.y ? liQ : liI;
  int wv = threadIdx.x >> 6, lane = threadIdx.x & 63;
  int pt = blockIdx.x * 4 + wv;
  float px = xy[pt * 2], py = xy[pt * 2 + 1];
  float s[16];
  float m = -1e30f;
  #pragma unroll
  for (int k = 0; k < 16; k++) {
    int n = lane + 64 * k;
    float2 np = ((const float2*)npos)[n];
    float dx = px - np.x, dy = py - np.y;
    float v = -(dx * dx + dy * dy);
    s[k] = v; m = fmaxf(m, v);
  }
  #pragma unroll
  for (int o = 32; o; o >>= 1) m = fmaxf(m, __shfl_xor(m, o));
  float l = 0.f;
  #pragma unroll
  for (int k = 0; k < 16; k++) l += __expf(s[k] - m);
  #pragma unroll
  for (int o = 32; o; o >>= 1) l += __shfl_xor(l, o);
  if (lane == 0) { mOut[pt] = m; liOut[pt] = 1.0f / l; }
}

// ---------------- weight prepack: WT[kc][n][kk] bf16 hi+lo ----------------
__global__ __launch_bounds__(256) void k_pack_w(const float* __restrict__ We2,
    const float* __restrict__ Wg, const float* __restrict__ Wd1,
    unsigned short* __restrict__ WTe2h, unsigned short* __restrict__ WTe2l,
    unsigned short* __restrict__ WTgh, unsigned short* __restrict__ WTgl,
    unsigned short* __restrict__ WTd1h, unsigned short* __restrict__ WTd1l) {
  int kc = blockIdx.x, which = blockIdx.y, n = threadIdx.x;
  const float* W = (which == 0) ? We2 : (which == 1) ? (Wg + 2 * FF) : Wd1;
  unsigned short* Dh = (which == 0) ? WTe2h : (which == 1) ? WTgh : WTd1h;
  unsigned short* Dl = (which == 0) ? WTe2l : (which == 1) ? WTgl : WTd1l;
  unsigned hu[16], lu[16];
  #pragma unroll
  for (int i = 0; i < 16; i++) {
    float a = W[(kc * 32 + 2 * i) * FF + n];
    float b = W[(kc * 32 + 2 * i + 1) * FF + n];
    split_pk(a, b, hu[i], lu[i]);
  }
  u32x4_t* dvh = (u32x4_t*)(Dh + ((size_t)kc * 256 + n) * 32);
  u32x4_t* dvl = (u32x4_t*)(Dl + ((size_t)kc * 256 + n) * 32);
  #pragma unroll
  for (int i = 0; i < 4; i++) {
    u32x4_t th = {hu[4 * i], hu[4 * i + 1], hu[4 * i + 2], hu[4 * i + 3]};
    u32x4_t tl = {lu[4 * i], lu[4 * i + 1], lu[4 * i + 2], lu[4 * i + 3]};
    dvh[i] = th; dvl[i] = tl;
  }
}

// ---------------- encoder: L1 fp32 VALU, L2 split-MFMA; writes encT hi+lo ----------------
__global__ __launch_bounds__(256) void k_encoder(const float* __restrict__ inx,
    const float* __restrict__ iny, const float* __restrict__ We1,
    const float* __restrict__ be1, const unsigned short* __restrict__ WTe2h,
    const unsigned short* __restrict__ WTe2l, const float* __restrict__ be2,
    unsigned short* __restrict__ encTh, unsigned short* __restrict__ encTl) {
  __shared__ float xin[32][8];
  __shared__ float h[32][TS];
  __shared__ unsigned short Bh[8192];
  __shared__ unsigned short Bl[8192];
  int tid = threadIdx.x;
  int row0 = blockIdx.x * 32;
  int wv = tid >> 6, L = tid & 63, lhi = L >> 4, llo = L & 15;

  if (tid < 160) {
    int pt = tid / 5, d = tid % 5;
    int r = row0 + pt;
    xin[pt][d] = (d < 2) ? inx[r * 2 + d] : iny[r * 3 + (d - 2)];
  }
  __syncthreads();
  {
    int f = tid;
    float w0 = We1[f], w1 = We1[256 + f], w2 = We1[512 + f], w3 = We1[768 + f], w4 = We1[1024 + f];
    float bb = be1[f];
    #pragma unroll 4
    for (int pt = 0; pt < 32; pt++) {
      float v = bb + xin[pt][0]*w0 + xin[pt][1]*w1 + xin[pt][2]*w2 + xin[pt][3]*w3 + xin[pt][4]*w4;
      h[pt][f] = fmaxf(v, 0.f);
    }
  }

  f32x4_t acc[2][4];
  #pragma unroll
  for (int cb = 0; cb < 4; cb++) {
    float bc = be2[wv * 64 + cb * 16 + llo];
    f32x4_t t = {bc, bc, bc, bc};
    acc[0][cb] = t; acc[1][cb] = t;
  }

  for (int kc = 0; kc < 8; kc++) {
    __syncthreads();
    {
      const u32x4_t* sh = (const u32x4_t*)(WTe2h + (size_t)kc * 8192);
      const u32x4_t* sl = (const u32x4_t*)(WTe2l + (size_t)kc * 8192);
      u32x4_t* dh = (u32x4_t*)Bh;
      u32x4_t* dl = (u32x4_t*)Bl;
      #pragma unroll
      for (int i = 0; i < 4; i++) {
        int e = tid + i * 256;
        int es = swz16(e);
        dh[es] = sh[e]; dl[es] = sl[e];
      }
    }
    __syncthreads();
    int kbase = kc * 32 + lhi * 8;
    u32x4_t a0h, a0l, a1h, a1l;
    {
      float p[8];
      *(f32x4_t*)p = *(const f32x4_t*)&h[llo][kbase];
      *(f32x4_t*)(p + 4) = *(const f32x4_t*)&h[llo][kbase + 4];
      unsigned hw[4], lw[4];
      #pragma unroll
      for (int i = 0; i < 4; i++) split_pk(p[2 * i], p[2 * i + 1], hw[i], lw[i]);
      u32x4_t th = {hw[0], hw[1], hw[2], hw[3]}; a0h = th;
      u32x4_t tl = {lw[0], lw[1], lw[2], lw[3]}; a0l = tl;
    }
    {
      float p[8];
      *(f32x4_t*)p = *(const f32x4_t*)&h[llo + 16][kbase];
      *(f32x4_t*)(p + 4) = *(const f32x4_t*)&h[llo + 16][kbase + 4];
      unsigned hw[4], lw[4];
      #pragma unroll
      for (int i = 0; i < 4; i++) split_pk(p[2 * i], p[2 * i + 1], hw[i], lw[i]);
      u32x4_t th = {hw[0], hw[1], hw[2], hw[3]}; a1h = th;
      u32x4_t tl = {lw[0], lw[1], lw[2], lw[3]}; a1l = tl;
    }
    #pragma unroll
    for (int cb = 0; cb < 4; cb++) {
      int col = wv * 64 + cb * 16 + llo;
      int off = swz16(col * 4 + lhi) * 8;
      u32x4_t bh = *(const u32x4_t*)&Bh[off];
      u32x4_t bl = *(const u32x4_t*)&Bl[off];
      acc[0][cb] = mfma16(a0h, bh, mfma16(a0h, bl, mfma16(a0l, bh, acc[0][cb])));
      acc[1][cb] = mfma16(a1h, bh, mfma16(a1h, bl, mfma16(a1l, bh, acc[1][cb])));
    }
  }
  #pragma unroll
  for (int rb = 0; rb < 2; rb++)
    #pragma unroll
    for (int cb = 0; cb < 4; cb++) {
      int col = wv * 64 + cb * 16 + llo;
      f32x4_t v = acc[rb][cb];
      size_t idx = ((size_t)blockIdx.x * 256 + col) * 32 + rb * 16 + lhi * 4;
      unsigned hw0, lw0, hw1, lw1;
      split_pk(v[0], v[1], hw0, lw0);
      split_pk(v[2], v[3], hw1, lw1);
      u32x2_t wh = {hw0, hw1}; *(u32x2_t*)&encTh[idx] = wh;
      u32x2_t wl = {lw0, lw1}; *(u32x2_t*)&encTl[idx] = wl;
    }
}

// ---------------- proj1 (split-K, 32-row tile, distance-2 reg prefetch) ----------------
__global__ __launch_bounds__(256, 4) void k_proj1(const float* __restrict__ inx,
    const float* __restrict__ mI, const float* __restrict__ liI,
    const float* __restrict__ npos, const unsigned short* __restrict__ encTh,
    const unsigned short* __restrict__ encTl, float* __restrict__ part) {
  __shared__ unsigned short BstH[8192];
  __shared__ unsigned short BstL[8192];
  __shared__ unsigned short AstH[1024];
  __shared__ unsigned short AstL[1024];
  int tid = threadIdx.x;
  int id = blockIdx.x;
  int xcd = id & 7, kid = id >> 3;
  int slice = xcd * 4 + (kid >> 5);
  int n0 = (kid & 31) * 32;
  int b = slice >> 2, z = slice & 3;
  int wv = tid >> 6, L = tid & 63, lhi = L >> 4, llo = L & 15;
  int an = tid >> 3, t7 = tid & 7, ap = t7 * 4;
  float2 npv = ((const float2*)npos)[n0 + an];
  int pbase0 = b * NP + z * 1024;
  int aoff = swz16(an * 4 + (t7 >> 1)) * 8 + (t7 & 1) * 4;

  u32x4_t rbhA[4], rblA[4], rbhB[4], rblB[4];
  unsigned chA0, chA1, clA0, clA1, chB0, chB1, clB0, clB1;

  auto coordA = [&](int kc, unsigned& h0, unsigned& l0, unsigned& h1, unsigned& l1) {
    int p = pbase0 + kc * 32 + ap;
    float c[4];
    #pragma unroll
    for (int j = 0; j < 4; j++) {
      float2 pxy = ((const float2*)inx)[p + j];
      float mm = mI[p + j], ll = liI[p + j];
      float dx = pxy.x - npv.x, dy = pxy.y - npv.y;
      c[j] = __expf(-(dx * dx + dy * dy) - mm) * ll;
    }
    split_pk(c[0], c[1], h0, l0);
    split_pk(c[2], c[3], h1, l1);
  };
  auto loadB = [&](int kc, u32x4_t rh[4], u32x4_t rl[4]) {
    const u32x4_t* sh = (const u32x4_t*)(encTh + (size_t)(b * 128 + z * 32 + kc) * 8192);
    const u32x4_t* sl = (const u32x4_t*)(encTl + (size_t)(b * 128 + z * 32 + kc) * 8192);
    #pragma unroll
    for (int i = 0; i < 4; i++) { rh[i] = sh[tid + i * 256]; rl[i] = sl[tid + i * 256]; }
  };
  auto putLDS = [&](const u32x4_t rh[4], const u32x4_t rl[4],
                    unsigned h0, unsigned l0, unsigned h1, unsigned l1) {
    #pragma unroll
    for (int i = 0; i < 4; i++) {
      int es = swz16(tid + i * 256);
      ((u32x4_t*)BstH)[es] = rh[i];
      ((u32x4_t*)BstL)[es] = rl[i];
    }
    u32x2_t wh = {h0, h1}; *(u32x2_t*)&AstH[aoff] = wh;
    u32x2_t wl = {l0, l1}; *(u32x2_t*)&AstL[aoff] = wl;
  };

  f32x4_t acc[2][4];
  #pragma unroll
  for (int i = 0; i < 2; i++)
    #pragma unroll
    for (int j = 0; j < 4; j++) { f32x4_t t = {0.f, 0.f, 0.f, 0.f}; acc[i][j] = t; }

  int a0off = swz16(llo * 4 + lhi) * 8;
  int a1off = swz16((llo + 16) * 4 + lhi) * 8;
  auto mm = [&]() {
    u32x4_t a0h = *(const u32x4_t*)&AstH[a0off];
    u32x4_t a0l = *(const u32x4_t*)&AstL[a0off];
    u32x4_t a1h = *(const u32x4_t*)&AstH[a1off];
    u32x4_t a1l = *(const u32x4_t*)&AstL[a1off];
    #pragma unroll
    for (int cb = 0; cb < 4; cb++) {
      int off = swz16((wv * 64 + cb * 16 + llo) * 4 + lhi) * 8;
      u32x4_t bh = *(const u32x4_t*)&BstH[off];
      u32x4_t bl = *(const u32x4_t*)&BstL[off];
      acc[0][cb] = mfma16(a0h, bh, mfma16(a0h, bl, mfma16(a0l, bh, acc[0][cb])));
      acc[1][cb] = mfma16(a1h, bh, mfma16(a1h, bl, mfma16(a1l, bh, acc[1][cb])));
    }
  };

  coordA(0, chA0, clA0, chA1, clA1); loadB(0, rbhA, rblA);
  coordA(1, chB0, clB0, chB1, clB1); loadB(1, rbhB, rblB);
  for (int kc = 0; kc < 32; kc += 2) {
    __syncthreads();
    putLDS(rbhA, rblA, chA0, clA0, chA1, clA1);
    __syncthreads();
    if (kc + 2 < 32) { loadB(kc + 2, rbhA, rblA); coordA(kc + 2, chA0, clA0, chA1, clA1); }
    mm();
    __syncthreads();
    putLDS(rbhB, rblB, chB0, clB0, chB1, clB1);
    __syncthreads();
    if (kc + 3 < 32) { loadB(kc + 3, rbhB, rblB); coordA(kc + 3, chB0, clB0, chB1, clB1); }
    mm();
  }
  float* op = part + (((size_t)(z * BB + b)) * NN + n0) * FF;
  #pragma unroll
  for (int rb = 0; rb < 2; rb++)
    #pragma unroll
    for (int cb = 0; cb < 4; cb++) {
      int col = wv * 64 + cb * 16 + llo;
      f32x4_t v = acc[rb][cb];
      #pragma unroll
      for (int r = 0; r < 4; r++) op[(rb * 16 + lhi * 4 + r) * FF + col] = v[r];
    }
}

// reduce split-K parts -> x (fp32)
__global__ __launch_bounds__(256) void k_reduce(const float* __restrict__ part,
                                                float* __restrict__ x) {
  size_t i = ((size_t)blockIdx.x * 256 + threadIdx.x) * 4;
  const size_t S = (size_t)BB * NN * FF;
  f32x4_t a = *(const f32x4_t*)&part[i];
  f32x4_t b = *(const f32x4_t*)&part[S + i];
  f32x4_t c = *(const f32x4_t*)&part[2 * S + i];
  f32x4_t d = *(const f32x4_t*)&part[3 * S + i];
  f32x4_t r = (a + b) + (c + d);
  *(f32x4_t*)&x[i] = r;
}

// ---------------- fused msg step (512 thr, LDS edge staging, reg-staged dbuf) ----------------
__global__ __launch_bounds__(512) void k_msg2(const float* __restrict__ x_in,
    float* __restrict__ x_out, const float* __restrict__ sposW,
    const int* __restrict__ coff, const int* __restrict__ csrc,
    const float* __restrict__ csw, const unsigned short* __restrict__ WTgh,
    const unsigned short* __restrict__ WTgl, const float* __restrict__ lng,
    const float* __restrict__ lnb, int last,
    unsigned short* __restrict__ xTh, unsigned short* __restrict__ xTl) {
  __shared__ unsigned Ah[32][132];
  __shared__ unsigned Al[32][132];
  __shared__ unsigned short Bh[2][8192];
  __shared__ unsigned short Bl[2][8192];
  __shared__ float redS[32][8];
  __shared__ float redQ[32][8];
  __shared__ int sed[EMAX];
  __shared__ float wed[EMAX];
  int tid = threadIdx.x;
  int id = blockIdx.x;
  int b = id & 7;
  int nb = id >> 3;
  int n0 = nb * 32;
  int wv = tid >> 6, L = tid & 63, lhi = L >> 4, llo = L & 15;

  u32x4_t rbh[2], rbl[2];
  auto loadB = [&](int kc) {
    const u32x4_t* sh = (const u32x4_t*)(WTgh + (size_t)kc * 8192);
    const u32x4_t* sl = (const u32x4_t*)(WTgl + (size_t)kc * 8192);
    #pragma unroll
    for (int i = 0; i < 2; i++) { rbh[i] = sh[tid + i * 512]; rbl[i] = sl[tid + i * 512]; }
  };
  auto writeB = [&](int buf) {
    u32x4_t* dh = (u32x4_t*)Bh[buf];
    u32x4_t* dl = (u32x4_t*)Bl[buf];
    #pragma unroll
    for (int i = 0; i < 2; i++) {
      int es = swz16(tid + i * 512);
      dh[es] = rbh[i]; dl[es] = rbl[i];
    }
  };

  loadB(0);   // in flight during edge staging + gather

  int e0b = coff[n0];
  int ecnt = coff[n0 + 32] - e0b;
  for (int i = tid; i < ecnt && i < EMAX; i += 512) {
    sed[i] = csrc[e0b + i];
    wed[i] = csw[e0b + i];
  }
  __syncthreads();

  {
    int row = tid >> 4, seg = tid & 15;
    int n = n0 + row;
    float g[16];
    #pragma unroll
    for (int i = 0; i < 16; i++) g[i] = 0.f;
    int e0 = coff[n] - e0b, e1 = coff[n + 1] - e0b;
    for (int e = e0; e < e1; e++) {
      int s; float w;
      if (e < EMAX) { s = sed[e]; w = wed[e]; }
      else { s = csrc[e0b + e]; w = csw[e0b + e]; }
      const f32x4_t* px = (const f32x4_t*)(x_in + ((size_t)b * NN + s) * FF + seg * 16);
      #pragma unroll
      for (int i = 0; i < 4; i++) {
        f32x4_t v = px[i];
        g[4*i]   += w * v[0]; g[4*i+1] += w * v[1];
        g[4*i+2] += w * v[2]; g[4*i+3] += w * v[3];
      }
    }
    #pragma unroll
    for (int i = 0; i < 8; i++) {
      unsigned h, l;
      split_pk(g[2 * i], g[2 * i + 1], h, l);
      Ah[row][seg * 8 + i] = h;
      Al[row][seg * 8 + i] = l;
    }
  }
  writeB(0);

  f32x4_t szr[2][2];
  #pragma unroll
  for (int rb = 0; rb < 2; rb++)
    #pragma unroll
    for (int cb = 0; cb < 2; cb++) {
      int col = wv * 32 + cb * 16 + llo;
      #pragma unroll
      for (int r = 0; r < 4; r++) {
        int row = rb * 16 + lhi * 4 + r;
        szr[rb][cb][r] = sposW[(size_t)(n0 + row) * FF + col]
                       + x_in[((size_t)b * NN + n0 + row) * FF + col];
      }
    }
  __syncthreads();

  f32x4_t acc[2][2];
  #pragma unroll
  for (int i = 0; i < 2; i++)
    #pragma unroll
    for (int j = 0; j < 2; j++) { f32x4_t t = {0.f, 0.f, 0.f, 0.f}; acc[i][j] = t; }

  for (int kc = 0; kc < 8; kc++) {
    int cur = kc & 1;
    if (kc < 7) loadB(kc + 1);
    u32x4_t a0h = *(const u32x4_t*)&Ah[llo][kc * 16 + lhi * 4];
    u32x4_t a0l = *(const u32x4_t*)&Al[llo][kc * 16 + lhi * 4];
    u32x4_t a1h = *(const u32x4_t*)&Ah[llo + 16][kc * 16 + lhi * 4];
    u32x4_t a1l = *(const u32x4_t*)&Al[llo + 16][kc * 16 + lhi * 4];
    #pragma unroll
    for (int cb = 0; cb < 2; cb++) {
      int off = swz16((wv * 32 + cb * 16 + llo) * 4 + lhi) * 8;
      u32x4_t bh = *(const u32x4_t*)&Bh[cur][off];
      u32x4_t bl = *(const u32x4_t*)&Bl[cur][off];
      acc[0][cb] = mfma16(a0h, bh, mfma16(a0h, bl, mfma16(a0l, bh, acc[0][cb])));
      acc[1][cb] = mfma16(a1h, bh, mfma16(a1h, bl, mfma16(a1l, bh, acc[1][cb])));
    }
    if (kc < 7) writeB(cur ^ 1);
    __syncthreads();
  }

  #pragma unroll
  for (int rb = 0; rb < 2; rb++)
    #pragma unroll
    for (int cb = 0; cb < 2; cb++) {
      #pragma unroll
      for (int r = 0; r < 4; r++) acc[rb][cb][r] += szr[rb][cb][r];
    }
  float ps[2][4], pq[2][4];
  #pragma unroll
  for (int rb = 0; rb < 2; rb++)
    #pragma unroll
    for (int r = 0; r < 4; r++) {
      float s = 0.f, q = 0.f;
      #pragma unroll
      for (int cb = 0; cb < 2; cb++) { float y = acc[rb][cb][r]; s += y; q += y * y; }
      #pragma unroll
      for (int m = 1; m < 16; m <<= 1) { s += __shfl_xor(s, m); q += __shfl_xor(q, m); }
      ps[rb][r] = s; pq[rb][r] = q;
    }
  if (llo == 0) {
    #pragma unroll
    for (int rb = 0; rb < 2; rb++)
      #pragma unroll
      for (int r = 0; r < 4; r++) {
        int row = rb * 16 + lhi * 4 + r;
        redS[row][wv] = ps[rb][r];
        redQ[row][wv] = pq[rb][r];
      }
  }
  __syncthreads();
  float mrs[2][4][2];
  #pragma unroll
  for (int rb = 0; rb < 2; rb++)
    #pragma unroll
    for (int r = 0; r < 4; r++) {
      int row = rb * 16 + lhi * 4 + r;
      float S = 0.f, Q = 0.f;
      #pragma unroll
      for (int wq = 0; wq < 8; wq++) { S += redS[row][wq]; Q += redQ[row][wq]; }
      float mean = S * (1.f / 256.f);
      float var = Q * (1.f / 256.f) - mean * mean;
      mrs[rb][r][0] = mean;
      mrs[rb][r][1] = rsqrtf(var + 1e-5f);
    }
  #pragma unroll
  for (int cb = 0; cb < 2; cb++) {
    int col = wv * 32 + cb * 16 + llo;
    float gg = lng[col], bb = lnb[col];
    #pragma unroll
    for (int rb = 0; rb < 2; rb++)
      #pragma unroll
      for (int r = 0; r < 4; r++) {
        int row = rb * 16 + lhi * 4 + r;
        float o = (acc[rb][cb][r] - mrs[rb][r][0]) * mrs[rb][r][1] * gg + bb;
        if (!last) {
          x_out[((size_t)b * NN + n0 + row) * FF + col] = o;
        } else {
          size_t idx = (((size_t)b * 32 + nb) * 256 + col) * 32 + row;
          unsigned short hh = f2bf(o);
          xTh[idx] = hh;
          xTl[idx] = f2bf(o - ashf(hh));
        }
      }
  }
}

// ---------------- proj2 (64-row tile, distance-2 reg prefetch) ----------------
__global__ __launch_bounds__(256, 3) void k_proj2(const float* __restrict__ qxy,
    const float* __restrict__ mQ, const float* __restrict__ liQ,
    const float* __restrict__ npos, const unsigned short* __restrict__ xTh,
    const unsigned short* __restrict__ xTl, unsigned short* __restrict__ latTh,
    unsigned short* __restrict__ latTl) {
  __shared__ unsigned short BstH[8192];
  __shared__ unsigned short BstL[8192];
  __shared__ unsigned short AstH[2048];
  __shared__ unsigned short AstL[2048];
  __shared__ float nps[NN * 2];
  int tid = threadIdx.x;
  int id = blockIdx.x;
  int b = id & 7;
  int q64 = id >> 3;             // 0..63 (64-row block)
  int q0 = q64 * 64;
  int wv = tid >> 6, L = tid & 63, lhi = L >> 4, llo = L & 15;
  int aq = tid >> 2, t3 = tid & 3, an8 = t3 * 8;
  int aoff = swz16(aq * 4 + t3) * 8;

  {
    const f32x4_t* s4 = (const f32x4_t*)npos;
    *(f32x4_t*)&nps[tid * 4] = s4[tid];
    *(f32x4_t*)&nps[(tid + 256) * 4] = s4[tid + 256];
  }
  int qg = b * NP + q0 + aq;
  float2 qv = ((const float2*)qxy)[qg];
  float qm = mQ[qg], qli = liQ[qg];
  __syncthreads();

  u32x4_t rbhA[4], rblA[4], rbhB[4], rblB[4];
  u32x4_t chvA, clvA, chvB, clvB;

  auto coordA = [&](int kc, u32x4_t& hv, u32x4_t& lv) {
    int nb = kc * 32 + an8;
    float c[8];
    #pragma unroll
    for (int j = 0; j < 8; j++) {
      float nx = nps[(nb + j) * 2], ny = nps[(nb + j) * 2 + 1];
      float dx = qv.x - nx, dy = qv.y - ny;
      c[j] = __expf(-(dx * dx + dy * dy) - qm) * qli;
    }
    unsigned h[4], l[4];
    #pragma unroll
    for (int j = 0; j < 4; j++) split_pk(c[2 * j], c[2 * j + 1], h[j], l[j]);
    u32x4_t th = {h[0], h[1], h[2], h[3]}; hv = th;
    u32x4_t tl = {l[0], l[1], l[2], l[3]}; lv = tl;
  };
  auto loadB = [&](int kc, u32x4_t rh[4], u32x4_t rl[4]) {
    const u32x4_t* sh = (const u32x4_t*)(xTh + (size_t)(b * 32 + kc) * 8192);
    const u32x4_t* sl = (const u32x4_t*)(xTl + (size_t)(b * 32 + kc) * 8192);
    #pragma unroll
    for (int i = 0; i < 4; i++) { rh[i] = sh[tid + i * 256]; rl[i] = sl[tid + i * 256]; }
  };
  auto putLDS = [&](const u32x4_t rh[4], const u32x4_t rl[4],
                    u32x4_t hv, u32x4_t lv) {
    #pragma unroll
    for (int i = 0; i < 4; i++) {
      int es = swz16(tid + i * 256);
      ((u32x4_t*)BstH)[es] = rh[i];
      ((u32x4_t*)BstL)[es] = rl[i];
    }
    *(u32x4_t*)&AstH[aoff] = hv;
    *(u32x4_t*)&AstL[aoff] = lv;
  };

  f32x4_t acc[4][4];
  #pragma unroll
  for (int i = 0; i < 4; i++)
    #pragma unroll
    for (int j = 0; j < 4; j++) { f32x4_t t = {0.f, 0.f, 0.f, 0.f}; acc[i][j] = t; }

  int aroff[4];
  #pragma unroll
  for (int rb = 0; rb < 4; rb++) aroff[rb] = swz16((llo + 16 * rb) * 4 + lhi) * 8;
  auto mm = [&]() {
    u32x4_t ah[4], al[4];
    #pragma unroll
    for (int rb = 0; rb < 4; rb++) {
      ah[rb] = *(const u32x4_t*)&AstH[aroff[rb]];
      al[rb] = *(const u32x4_t*)&AstL[aroff[rb]];
    }
    #pragma unroll
    for (int cb = 0; cb < 4; cb++) {
      int off = swz16((wv * 64 + cb * 16 + llo) * 4 + lhi) * 8;
      u32x4_t bh = *(const u32x4_t*)&BstH[off];
      u32x4_t bl = *(const u32x4_t*)&BstL[off];
      #pragma unroll
      for (int rb = 0; rb < 4; rb++)
        acc[rb][cb] = mfma16(ah[rb], bh, mfma16(ah[rb], bl, mfma16(al[rb], bh, acc[rb][cb])));
    }
  };

  coordA(0, chvA, clvA); loadB(0, rbhA, rblA);
  coordA(1, chvB, clvB); loadB(1, rbhB, rblB);
  for (int kc = 0; kc < 32; kc += 2) {
    __syncthreads();
    putLDS(rbhA, rblA, chvA, clvA);
    __syncthreads();
    if (kc + 2 < 32) { loadB(kc + 2, rbhA, rblA); coordA(kc + 2, chvA, clvA); }
    mm();
    __syncthreads();
    putLDS(rbhB, rblB, chvB, clvB);
    __syncthreads();
    if (kc + 3 < 32) { loadB(kc + 3, rbhB, rblB); coordA(kc + 3, chvB, clvB); }
    mm();
  }
  #pragma unroll
  for (int rb = 0; rb < 4; rb++)
    #pragma unroll
    for (int cb = 0; cb < 4; cb++) {
      int col = wv * 64 + cb * 16 + llo;
      int fc = col >> 5, kk = col & 31;
      f32x4_t v = acc[rb][cb];
      #pragma unroll
      for (int r = 0; r < 4; r++) {
        int row = rb * 16 + lhi * 4 + r;                 // 0..63
        int bt = b * 128 + q64 * 2 + (row >> 5);
        size_t idx = ((size_t)bt * 8 + fc) * 1024 + (row & 31) * 32 + kk;
        unsigned short hh = f2bf(v[r]);
        latTh[idx] = hh;
        latTl[idx] = f2bf(v[r] - ashf(hh));
      }
    }
}

// ---------------- decoder (single-buffer LDS + reg prefetch) ----------------
__global__ __launch_bounds__(256, 4) void k_decoder(const unsigned short* __restrict__ latTh,
    const unsigned short* __restrict__ latTl, const float* __restrict__ qxy,
    const unsigned short* __restrict__ WTd1h, const unsigned short* __restrict__ WTd1l,
    const float* __restrict__ bd1, const float* __restrict__ Wd1,
    const float* __restrict__ Wd2, const float* __restrict__ bd2, float* __restrict__ out) {
  __shared__ unsigned short BstH[8192];
  __shared__ unsigned short BstL[8192];
  __shared__ unsigned short AstH[1024];
  __shared__ unsigned short AstL[1024];
  __shared__ float qs[32][2];
  __shared__ float red[4][32][3];
  int tid = threadIdx.x;
  int bt = blockIdx.x;
  int wv = tid >> 6, L = tid & 63, lhi = L >> 4, llo = L & 15;

  u32x4_t rbh[4], rbl[4], ra;
  auto loadB = [&](int kc) {
    const u32x4_t* sh = (const u32x4_t*)(WTd1h + (size_t)kc * 8192);
    const u32x4_t* sl = (const u32x4_t*)(WTd1l + (size_t)kc * 8192);
    #pragma unroll
    for (int i = 0; i < 4; i++) { rbh[i] = sh[tid + i * 256]; rbl[i] = sl[tid + i * 256]; }
  };
  auto loadA = [&](int kc) {
    if (tid < 128)
      ra = ((const u32x4_t*)(latTh + ((size_t)bt * 8 + kc) * 1024))[tid];
    else
      ra = ((const u32x4_t*)(latTl + ((size_t)bt * 8 + kc) * 1024))[tid - 128];
  };

  if (tid < 64) qs[tid >> 1][tid & 1] = qxy[((size_t)bt * 32 + (tid >> 1)) * 2 + (tid & 1)];
  loadB(0); loadA(0);
  __syncthreads();

  f32x4_t acc[2][4];
  #pragma unroll
  for (int cb = 0; cb < 4; cb++) {
    int col = wv * 64 + cb * 16 + llo;
    float wa = Wd1[256 * FF + col], wb = Wd1[257 * FF + col], bc = bd1[col];
    #pragma unroll
    for (int rb = 0; rb < 2; rb++) {
      f32x4_t t;
      #pragma unroll
      for (int r = 0; r < 4; r++) {
        int row = rb * 16 + lhi * 4 + r;
        t[r] = bc + qs[row][0] * wa + qs[row][1] * wb;
      }
      acc[rb][cb] = t;
    }
  }

  int a0off = swz16(llo * 4 + lhi) * 8;
  int a1off = swz16((llo + 16) * 4 + lhi) * 8;
  for (int kc = 0; kc < 8; kc++) {
    __syncthreads();
    #pragma unroll
    for (int i = 0; i < 4; i++) {
      int es = swz16(tid + i * 256);
      ((u32x4_t*)BstH)[es] = rbh[i];
      ((u32x4_t*)BstL)[es] = rbl[i];
    }
    if (tid < 128) ((u32x4_t*)AstH)[swz16(tid)] = ra;
    else ((u32x4_t*)AstL)[swz16(tid - 128)] = ra;
    __syncthreads();
    if (kc < 7) { loadB(kc + 1); loadA(kc + 1); }
    u32x4_t a0h = *(const u32x4_t*)&AstH[a0off];
    u32x4_t a0l = *(const u32x4_t*)&AstL[a0off];
    u32x4_t a1h = *(const u32x4_t*)&AstH[a1off];
    u32x4_t a1l = *(const u32x4_t*)&AstL[a1off];
    #pragma unroll
    for (int cb = 0; cb < 4; cb++) {
      int off = swz16((wv * 64 + cb * 16 + llo) * 4 + lhi) * 8;
      u32x4_t bh = *(const u32x4_t*)&BstH[off];
      u32x4_t bl = *(const u32x4_t*)&BstL[off];
      acc[0][cb] = mfma16(a0h, bh, mfma16(a0h, bl, mfma16(a0l, bh, acc[0][cb])));
      acc[1][cb] = mfma16(a1h, bh, mfma16(a1h, bl, mfma16(a1l, bh, acc[1][cb])));
    }
  }

  float po[2][4][3];
  #pragma unroll
  for (int rb = 0; rb < 2; rb++)
    #pragma unroll
    for (int r = 0; r < 4; r++) { po[rb][r][0] = 0.f; po[rb][r][1] = 0.f; po[rb][r][2] = 0.f; }
  #pragma unroll
  for (int rb = 0; rb < 2; rb++)
    #pragma unroll
    for (int cb = 0; cb < 4; cb++) {
      int col = wv * 64 + cb * 16 + llo;
      float w0 = Wd2[col * 3], w1 = Wd2[col * 3 + 1], w2 = Wd2[col * 3 + 2];
      f32x4_t v = acc[rb][cb];
      #pragma unroll
      for (int r = 0; r < 4; r++) {
        float hv = fmaxf(v[r], 0.f);
        po[rb][r][0] += hv * w0; po[rb][r][1] += hv * w1; po[rb][r][2] += hv * w2;
      }
    }
  #pragma unroll
  for (int o = 8; o; o >>= 1)
    #pragma unroll
    for (int rb = 0; rb < 2; rb++)
      #pragma unroll
      for (int r = 0; r < 4; r++) {
        po[rb][r][0] += __shfl_xor(po[rb][r][0], o);
        po[rb][r][1] += __shfl_xor(po[rb][r][1], o);
        po[rb][r][2] += __shfl_xor(po[rb][r][2], o);
      }
  if (llo == 0) {
    #pragma unroll
    for (int rb = 0; rb < 2; rb++)
      #pragma unroll
      for (int r = 0; r < 4; r++) {
        int row = rb * 16 + lhi * 4 + r;
        red[wv][row][0] = po[rb][r][0];
        red[wv][row][1] = po[rb][r][1];
        red[wv][row][2] = po[rb][r][2];
      }
  }
  __syncthreads();
  if (tid < 96) {
    int row = tid / 3, o = tid % 3;
    float s = red[0][row][o] + red[1][row][o] + red[2][row][o] + red[3][row][o] + bd2[o];
    out[((size_t)bt * 32 + row) * 3 + o] = s;
  }
}

extern "C" void kernel_launch(void* const* d_in, const int* in_sizes, int n_in,
                              void* d_out, int out_size, void* d_ws, size_t ws_size,
                              hipStream_t stream) {
  const float* inx = (const float*)d_in[0];
  const float* iny = (const float*)d_in[1];
  const float* qxy = (const float*)d_in[2];
  const float* npos = (const float*)d_in[3];
  const float* We1 = (const float*)d_in[4];
  const float* be1 = (const float*)d_in[5];
  const float* We2 = (const float*)d_in[6];
  const float* be2 = (const float*)d_in[7];
  const float* Wg  = (const float*)d_in[8];
  const float* bg  = (const float*)d_in[9];
  const float* lng = (const float*)d_in[10];
  const float* lnb = (const float*)d_in[11];
  const float* Wd1 = (const float*)d_in[12];
  const float* bd1 = (const float*)d_in[13];
  const float* Wd2 = (const float*)d_in[14];
  const float* bd2 = (const float*)d_in[15];
  const int* eidx  = (const int*)d_in[16];
  float* out = (float*)d_out;

  char* w = (char*)d_ws;
  auto carve = [&](size_t n) { char* p = w; w += (n + 255) & ~(size_t)255; return p; };
  char* encR = carve((size_t)2 * BB * NP * FF * 2);                          // 32 MB
  unsigned short* encTh = (unsigned short*)encR;
  unsigned short* encTl = (unsigned short*)(encR + (size_t)BB * NP * FF * 2);
  unsigned short* latTh = encTh;   // alias (dead after proj1)
  unsigned short* latTl = encTl;
  float* xA = (float*)carve((size_t)BB * NN * FF * 4);                       // 8 MB
  float* xB = (float*)carve((size_t)BB * NN * FF * 4);                       // 8 MB
  unsigned short* xTh = (unsigned short*)carve((size_t)BB * NN * FF * 2);    // 4 MB
  unsigned short* xTl = (unsigned short*)carve((size_t)BB * NN * FF * 2);    // 4 MB
  float* part = (float*)carve((size_t)4 * BB * NN * FF * 4);                 // 32 MB
  float* mI   = (float*)carve((size_t)BB * NP * 4);
  float* liI  = (float*)carve((size_t)BB * NP * 4);
  float* mQ   = (float*)carve((size_t)BB * NP * 4);
  float* liQ  = (float*)carve((size_t)BB * NP * 4);
  unsigned short* WTe2h = (unsigned short*)carve((size_t)8 * 256 * 32 * 2);
  unsigned short* WTe2l = (unsigned short*)carve((size_t)8 * 256 * 32 * 2);
  unsigned short* WTgh  = (unsigned short*)carve((size_t)8 * 256 * 32 * 2);
  unsigned short* WTgl  = (unsigned short*)carve((size_t)8 * 256 * 32 * 2);
  unsigned short* WTd1h = (unsigned short*)carve((size_t)8 * 256 * 32 * 2);
  unsigned short* WTd1l = (unsigned short*)carve((size_t)8 * 256 * 32 * 2);
  float* sposW = (float*)carve((size_t)NN * FF * 4);
  float* dinv = (float*)carve(NN * 4);
  float* csw  = (float*)carve((NE + NN) * 4);
  int* coff   = (int*)carve((NN + 1) * 4);
  int* csrc   = (int*)carve((NE + NN) * 4);
  int* cntg   = (int*)carve((size_t)NSEG * NN * 4);

  const int* esrc = eidx;
  const int* edst = eidx + NE;

  k_cnt<<<dim3(NSEG), dim3(1024), 0, stream>>>(edst, cntg);
  k_scan2<<<dim3(1), dim3(1024), 0, stream>>>(cntg, dinv, coff);
  k_fill2<<<dim3(NSEG + 1), dim3(1024), 0, stream>>>(esrc, edst, dinv, coff, cntg, csrc, csw);
  k_posb<<<dim3(NN), dim3(256), 0, stream>>>(npos, coff, csrc, csw, Wg, bg, sposW);
  k_pack_w<<<dim3(8, 3), dim3(256), 0, stream>>>(We2, Wg, Wd1, WTe2h, WTe2l, WTgh, WTgl,
                                                 WTd1h, WTd1l);

  k_stats<<<dim3(BB * NP / 4, 2), dim3(256), 0, stream>>>(inx, qxy, npos, mI, liI, mQ, liQ);
  k_encoder<<<dim3(BB * NP / 32), dim3(256), 0, stream>>>(inx, iny, We1, be1, WTe2h, WTe2l, be2,
                                                          encTh, encTl);
  k_proj1<<<dim3(1024), dim3(256), 0, stream>>>(inx, mI, liI, npos, encTh, encTl, part);
  k_reduce<<<dim3(BB * NN * FF / 1024), dim3(256), 0, stream>>>(part, xA);
  for (int s = 0; s < NSTEP; s++) {
    const float* xi = (s & 1) ? xB : xA;
    float* xo = (s & 1) ? xA : xB;
    k_msg2<<<dim3(256), dim3(512), 0, stream>>>(xi, xo, sposW, coff, csrc, csw,
                                                WTgh, WTgl, lng, lnb,
                                                (s == NSTEP - 1) ? 1 : 0, xTh, xTl);
  }
  k_proj2<<<dim3(512), dim3(256), 0, stream>>>(qxy, mQ, liQ, npos, xTh, xTl, latTh, latTl);
  k_decoder<<<dim3(BB * NP / 32), dim3(256), 0, stream>>>(latTh, latTl, qxy, WTd1h, WTd1l,
                                                          bd1, Wd1, Wd2, bd2, out);
}

// Round 16
// 532.442 us; speedup vs baseline: 1.3054x; 1.3054x over previous
//
#include <hip/hip_runtime.h>

#define BB 8
#define NP 4096    // NPTS == NQ
#define NN 1024
#define NE 8192
#define FF 256
#define TS 264
#define NSTEP 16
#define NSEG 64
#define SEGSZ 128  // NSEG*SEGSZ == NE
#define EMAX 1536  // per-block staged CSR records (mean ~288)

typedef float f32x4_t __attribute__((ext_vector_type(4)));
typedef __bf16 bf16x8_t __attribute__((ext_vector_type(8)));
typedef unsigned int u32x4_t __attribute__((ext_vector_type(4)));
typedef unsigned int u32x2_t __attribute__((ext_vector_type(2)));

// hardware RNE f32->bf16; bit-identical to SW round-to-nearest-even on normals
static __device__ __forceinline__ unsigned short f2bf(float f) {
  return __builtin_bit_cast(unsigned short, static_cast<__bf16>(f));
}
static __device__ __forceinline__ float ashf(unsigned short s) {
  union { unsigned u; float f; } t; t.u = (unsigned)s << 16; return t.f;
}
// split a,b into hi/lo bf16 pairs packed as u32
static __device__ __forceinline__ void split_pk(float a, float b, unsigned& h, unsigned& l) {
  unsigned short ha = f2bf(a), hb = f2bf(b);
  unsigned short la = f2bf(a - ashf(ha)), lb = f2bf(b - ashf(hb));
  h = (unsigned)ha | ((unsigned)hb << 16);
  l = (unsigned)la | ((unsigned)lb << 16);
}
static __device__ __forceinline__ f32x4_t mfma16(u32x4_t a, u32x4_t b, f32x4_t c) {
  return __builtin_amdgcn_mfma_f32_16x16x32_bf16(
      __builtin_bit_cast(bf16x8_t, a), __builtin_bit_cast(bf16x8_t, b), c, 0, 0, 0);
}
// 16B-entry XOR swizzle: spreads 64-byte fragment rows over all 32 LDS banks
static __device__ __forceinline__ int swz16(int e) { return e ^ ((e >> 3) & 7); }

// ---------------- graph preprocessing (segmented, deterministic) ----------------
__global__ __launch_bounds__(1024) void k_cnt(const int* __restrict__ dstA,
                                              int* __restrict__ cntg) {
  __shared__ int ds[SEGSZ];
  int seg = blockIdx.x, n = threadIdx.x;
  if (n < SEGSZ) ds[n] = dstA[seg * SEGSZ + n];
  __syncthreads();
  int c = 0;
  #pragma unroll 8
  for (int e = 0; e < SEGSZ; e++) c += (ds[e] == n) ? 1 : 0;
  cntg[seg * NN + n] = c;
}

__global__ __launch_bounds__(1024) void k_scan2(const int* __restrict__ cntg,
    float* __restrict__ dinv, int* __restrict__ csr_off) {
  __shared__ int s[NN];
  int n = threadIdx.x;
  int c = 1;
  for (int sg = 0; sg < NSEG; sg++) c += cntg[sg * NN + n];
  dinv[n] = rsqrtf((float)c);
  s[n] = c;
  __syncthreads();
  for (int st = 1; st < NN; st <<= 1) {
    int v = (n >= st) ? s[n - st] : 0;
    __syncthreads();
    s[n] += v;
    __syncthreads();
  }
  csr_off[n] = s[n] - c;
  if (n == NN - 1) csr_off[NN] = s[n];
}

__global__ __launch_bounds__(1024) void k_fill2(const int* __restrict__ srcA,
    const int* __restrict__ dstA, const float* __restrict__ dinv,
    const int* __restrict__ csr_off, const int* __restrict__ cntg,
    int* __restrict__ csr_src, float* __restrict__ csr_w) {
  int n = threadIdx.x;
  if (blockIdx.x == NSEG) {
    int pos = csr_off[n + 1] - 1;               // self loop last
    csr_src[pos] = n;
    csr_w[pos] = dinv[n] * dinv[n];
    return;
  }
  __shared__ int ds[SEGSZ], ss[SEGSZ];
  int seg = blockIdx.x;
  if (n < SEGSZ) { ds[n] = dstA[seg * SEGSZ + n]; ss[n] = srcA[seg * SEGSZ + n]; }
  __syncthreads();
  int base = csr_off[n];
  for (int s2 = 0; s2 < seg; s2++) base += cntg[s2 * NN + n];
  float dn = dinv[n];
  for (int e = 0; e < SEGSZ; e++) {
    if (ds[e] == n) {
      int sv = ss[e];
      csr_src[base] = sv;
      csr_w[base] = dinv[sv] * dn;
      base++;
    }
  }
}

// spos + sposW fused: one block per node n; spos sum recomputed redundantly per thread
__global__ __launch_bounds__(256) void k_posb(const float* __restrict__ npos,
    const int* __restrict__ csr_off, const int* __restrict__ csr_src,
    const float* __restrict__ csr_w, const float* __restrict__ Wg,
    const float* __restrict__ bg, float* __restrict__ sposW) {
  int n = blockIdx.x, f = threadIdx.x;
  float sx = 0.f, sy = 0.f;
  int e1 = csr_off[n + 1];
  for (int e = csr_off[n]; e < e1; e++) {
    float w = csr_w[e]; int s = csr_src[e];
    sx += w * npos[2 * s]; sy += w * npos[2 * s + 1];
  }
  sposW[(size_t)n * FF + f] = sx * Wg[f] + sy * Wg[FF + f] + bg[f];
}

// ---------------- softmax stats (inputs and queries in one launch) ----------------
__global__ __launch_bounds__(256) void k_stats(const float* __restrict__ inx,
    const float* __restrict__ qxy, const float* __restrict__ npos,
    float* __restrict__ mI, float* __restrict__ liI,
    float* __restrict__ mQ, float* __restrict__ liQ) {
  const float* xy = blockIdx.y ? qxy : inx;
  float* mOut = blockIdx.y ? mQ : mI;
  float* liOut = blockIdx.y ? liQ : liI;
  int wv = threadIdx.x >> 6, lane = threadIdx.x & 63;
  int pt = blockIdx.x * 4 + wv;
  float px = xy[pt * 2], py = xy[pt * 2 + 1];
  float s[16];
  float m = -1e30f;
  #pragma unroll
  for (int k = 0; k < 16; k++) {
    int n = lane + 64 * k;
    float2 np = ((const float2*)npos)[n];
    float dx = px - np.x, dy = py - np.y;
    float v = -(dx * dx + dy * dy);
    s[k] = v; m = fmaxf(m, v);
  }
  #pragma unroll
  for (int o = 32; o; o >>= 1) m = fmaxf(m, __shfl_xor(m, o));
  float l = 0.f;
  #pragma unroll
  for (int k = 0; k < 16; k++) l += __expf(s[k] - m);
  #pragma unroll
  for (int o = 32; o; o >>= 1) l += __shfl_xor(l, o);
  if (lane == 0) { mOut[pt] = m; liOut[pt] = 1.0f / l; }
}

// ---------------- weight prepack: WT[kc][n][kk] bf16 hi+lo ----------------
__global__ __launch_bounds__(256) void k_pack_w(const float* __restrict__ We2,
    const float* __restrict__ Wg, const float* __restrict__ Wd1,
    unsigned short* __restrict__ WTe2h, unsigned short* __restrict__ WTe2l,
    unsigned short* __restrict__ WTgh, unsigned short* __restrict__ WTgl,
    unsigned short* __restrict__ WTd1h, unsigned short* __restrict__ WTd1l) {
  int kc = blockIdx.x, which = blockIdx.y, n = threadIdx.x;
  const float* W = (which == 0) ? We2 : (which == 1) ? (Wg + 2 * FF) : Wd1;
  unsigned short* Dh = (which == 0) ? WTe2h : (which == 1) ? WTgh : WTd1h;
  unsigned short* Dl = (which == 0) ? WTe2l : (which == 1) ? WTgl : WTd1l;
  unsigned hu[16], lu[16];
  #pragma unroll
  for (int i = 0; i < 16; i++) {
    float a = W[(kc * 32 + 2 * i) * FF + n];
    float b = W[(kc * 32 + 2 * i + 1) * FF + n];
    split_pk(a, b, hu[i], lu[i]);
  }
  u32x4_t* dvh = (u32x4_t*)(Dh + ((size_t)kc * 256 + n) * 32);
  u32x4_t* dvl = (u32x4_t*)(Dl + ((size_t)kc * 256 + n) * 32);
  #pragma unroll
  for (int i = 0; i < 4; i++) {
    u32x4_t th = {hu[4 * i], hu[4 * i + 1], hu[4 * i + 2], hu[4 * i + 3]};
    u32x4_t tl = {lu[4 * i], lu[4 * i + 1], lu[4 * i + 2], lu[4 * i + 3]};
    dvh[i] = th; dvl[i] = tl;
  }
}

// ---------------- encoder: L1 fp32 VALU, L2 split-MFMA; writes encT hi+lo ----------------
__global__ __launch_bounds__(256) void k_encoder(const float* __restrict__ inx,
    const float* __restrict__ iny, const float* __restrict__ We1,
    const float* __restrict__ be1, const unsigned short* __restrict__ WTe2h,
    const unsigned short* __restrict__ WTe2l, const float* __restrict__ be2,
    unsigned short* __restrict__ encTh, unsigned short* __restrict__ encTl) {
  __shared__ float xin[32][8];
  __shared__ float h[32][TS];
  __shared__ unsigned short Bh[8192];
  __shared__ unsigned short Bl[8192];
  int tid = threadIdx.x;
  int row0 = blockIdx.x * 32;
  int wv = tid >> 6, L = tid & 63, lhi = L >> 4, llo = L & 15;

  if (tid < 160) {
    int pt = tid / 5, d = tid % 5;
    int r = row0 + pt;
    xin[pt][d] = (d < 2) ? inx[r * 2 + d] : iny[r * 3 + (d - 2)];
  }
  __syncthreads();
  {
    int f = tid;
    float w0 = We1[f], w1 = We1[256 + f], w2 = We1[512 + f], w3 = We1[768 + f], w4 = We1[1024 + f];
    float bb = be1[f];
    #pragma unroll 4
    for (int pt = 0; pt < 32; pt++) {
      float v = bb + xin[pt][0]*w0 + xin[pt][1]*w1 + xin[pt][2]*w2 + xin[pt][3]*w3 + xin[pt][4]*w4;
      h[pt][f] = fmaxf(v, 0.f);
    }
  }

  f32x4_t acc[2][4];
  #pragma unroll
  for (int cb = 0; cb < 4; cb++) {
    float bc = be2[wv * 64 + cb * 16 + llo];
    f32x4_t t = {bc, bc, bc, bc};
    acc[0][cb] = t; acc[1][cb] = t;
  }

  for (int kc = 0; kc < 8; kc++) {
    __syncthreads();
    {
      const u32x4_t* sh = (const u32x4_t*)(WTe2h + (size_t)kc * 8192);
      const u32x4_t* sl = (const u32x4_t*)(WTe2l + (size_t)kc * 8192);
      u32x4_t* dh = (u32x4_t*)Bh;
      u32x4_t* dl = (u32x4_t*)Bl;
      #pragma unroll
      for (int i = 0; i < 4; i++) {
        int e = tid + i * 256;
        int es = swz16(e);
        dh[es] = sh[e]; dl[es] = sl[e];
      }
    }
    __syncthreads();
    int kbase = kc * 32 + lhi * 8;
    u32x4_t a0h, a0l, a1h, a1l;
    {
      float p[8];
      *(f32x4_t*)p = *(const f32x4_t*)&h[llo][kbase];
      *(f32x4_t*)(p + 4) = *(const f32x4_t*)&h[llo][kbase + 4];
      unsigned hw[4], lw[4];
      #pragma unroll
      for (int i = 0; i < 4; i++) split_pk(p[2 * i], p[2 * i + 1], hw[i], lw[i]);
      u32x4_t th = {hw[0], hw[1], hw[2], hw[3]}; a0h = th;
      u32x4_t tl = {lw[0], lw[1], lw[2], lw[3]}; a0l = tl;
    }
    {
      float p[8];
      *(f32x4_t*)p = *(const f32x4_t*)&h[llo + 16][kbase];
      *(f32x4_t*)(p + 4) = *(const f32x4_t*)&h[llo + 16][kbase + 4];
      unsigned hw[4], lw[4];
      #pragma unroll
      for (int i = 0; i < 4; i++) split_pk(p[2 * i], p[2 * i + 1], hw[i], lw[i]);
      u32x4_t th = {hw[0], hw[1], hw[2], hw[3]}; a1h = th;
      u32x4_t tl = {lw[0], lw[1], lw[2], lw[3]}; a1l = tl;
    }
    #pragma unroll
    for (int cb = 0; cb < 4; cb++) {
      int col = wv * 64 + cb * 16 + llo;
      int off = swz16(col * 4 + lhi) * 8;
      u32x4_t bh = *(const u32x4_t*)&Bh[off];
      u32x4_t bl = *(const u32x4_t*)&Bl[off];
      acc[0][cb] = mfma16(a0h, bh, mfma16(a0h, bl, mfma16(a0l, bh, acc[0][cb])));
      acc[1][cb] = mfma16(a1h, bh, mfma16(a1h, bl, mfma16(a1l, bh, acc[1][cb])));
    }
  }
  #pragma unroll
  for (int rb = 0; rb < 2; rb++)
    #pragma unroll
    for (int cb = 0; cb < 4; cb++) {
      int col = wv * 64 + cb * 16 + llo;
      f32x4_t v = acc[rb][cb];
      size_t idx = ((size_t)blockIdx.x * 256 + col) * 32 + rb * 16 + lhi * 4;
      unsigned hw0, lw0, hw1, lw1;
      split_pk(v[0], v[1], hw0, lw0);
      split_pk(v[2], v[3], hw1, lw1);
      u32x2_t wh = {hw0, hw1}; *(u32x2_t*)&encTh[idx] = wh;
      u32x2_t wl = {lw0, lw1}; *(u32x2_t*)&encTl[idx] = wl;
    }
}

// ---------------- proj1 (split-K, 32-row tile, single-buffer LDS + reg prefetch) ----------------
__global__ __launch_bounds__(256, 4) void k_proj1(const float* __restrict__ inx,
    const float* __restrict__ mI, const float* __restrict__ liI,
    const float* __restrict__ npos, const unsigned short* __restrict__ encTh,
    const unsigned short* __restrict__ encTl, float* __restrict__ part) {
  __shared__ unsigned short BstH[8192];
  __shared__ unsigned short BstL[8192];
  __shared__ unsigned short AstH[1024];
  __shared__ unsigned short AstL[1024];
  int tid = threadIdx.x;
  // XCD-aware decode: each XCD owns 4 (b,z)-slices; 32 n-blocks per slice stay local
  int id = blockIdx.x;
  int xcd = id & 7, kid = id >> 3;
  int slice = xcd * 4 + (kid >> 5);
  int n0 = (kid & 31) * 32;
  int b = slice >> 2, z = slice & 3;
  int wv = tid >> 6, L = tid & 63, lhi = L >> 4, llo = L & 15;
  int an = tid >> 3, t7 = tid & 7, ap = t7 * 4;
  float2 npv = ((const float2*)npos)[n0 + an];
  int pbase0 = b * NP + z * 1024;
  int aoff = swz16(an * 4 + (t7 >> 1)) * 8 + (t7 & 1) * 4;

  u32x4_t rbh[4], rbl[4];
  unsigned ch0, ch1, cl0, cl1;

  auto coordA = [&](int kc) {
    int p = pbase0 + kc * 32 + ap;
    float c[4];
    #pragma unroll
    for (int j = 0; j < 4; j++) {
      float2 pxy = ((const float2*)inx)[p + j];
      float mm = mI[p + j], ll = liI[p + j];
      float dx = pxy.x - npv.x, dy = pxy.y - npv.y;
      c[j] = __expf(-(dx * dx + dy * dy) - mm) * ll;
    }
    split_pk(c[0], c[1], ch0, cl0);
    split_pk(c[2], c[3], ch1, cl1);
  };
  auto loadB = [&](int kc) {
    const u32x4_t* sh = (const u32x4_t*)(encTh + (size_t)(b * 128 + z * 32 + kc) * 8192);
    const u32x4_t* sl = (const u32x4_t*)(encTl + (size_t)(b * 128 + z * 32 + kc) * 8192);
    #pragma unroll
    for (int i = 0; i < 4; i++) { rbh[i] = sh[tid + i * 256]; rbl[i] = sl[tid + i * 256]; }
  };

  f32x4_t acc[2][4];
  #pragma unroll
  for (int i = 0; i < 2; i++)
    #pragma unroll
    for (int j = 0; j < 4; j++) { f32x4_t t = {0.f, 0.f, 0.f, 0.f}; acc[i][j] = t; }

  coordA(0);
  loadB(0);
  int a0off = swz16(llo * 4 + lhi) * 8;
  int a1off = swz16((llo + 16) * 4 + lhi) * 8;
  for (int kc = 0; kc < 32; kc++) {
    __syncthreads();                       // previous compute done reading LDS
    #pragma unroll
    for (int i = 0; i < 4; i++) {
      int es = swz16(tid + i * 256);
      ((u32x4_t*)BstH)[es] = rbh[i];
      ((u32x4_t*)BstL)[es] = rbl[i];
    }
    { u32x2_t wh = {ch0, ch1}; *(u32x2_t*)&AstH[aoff] = wh; }
    { u32x2_t wl = {cl0, cl1}; *(u32x2_t*)&AstL[aoff] = wl; }
    __syncthreads();
    if (kc < 31) { loadB(kc + 1); coordA(kc + 1); }   // in flight / co-issue during MFMA
    u32x4_t a0h = *(const u32x4_t*)&AstH[a0off];
    u32x4_t a0l = *(const u32x4_t*)&AstL[a0off];
    u32x4_t a1h = *(const u32x4_t*)&AstH[a1off];
    u32x4_t a1l = *(const u32x4_t*)&AstL[a1off];
    #pragma unroll
    for (int cb = 0; cb < 4; cb++) {
      int off = swz16((wv * 64 + cb * 16 + llo) * 4 + lhi) * 8;
      u32x4_t bh = *(const u32x4_t*)&BstH[off];
      u32x4_t bl = *(const u32x4_t*)&BstL[off];
      acc[0][cb] = mfma16(a0h, bh, mfma16(a0h, bl, mfma16(a0l, bh, acc[0][cb])));
      acc[1][cb] = mfma16(a1h, bh, mfma16(a1h, bl, mfma16(a1l, bh, acc[1][cb])));
    }
  }
  float* op = part + (((size_t)(z * BB + b)) * NN + n0) * FF;
  #pragma unroll
  for (int rb = 0; rb < 2; rb++)
    #pragma unroll
    for (int cb = 0; cb < 4; cb++) {
      int col = wv * 64 + cb * 16 + llo;
      f32x4_t v = acc[rb][cb];
      #pragma unroll
      for (int r = 0; r < 4; r++) op[(rb * 16 + lhi * 4 + r) * FF + col] = v[r];
    }
}

// reduce split-K parts -> x (fp32)
__global__ __launch_bounds__(256) void k_reduce(const float* __restrict__ part,
                                                float* __restrict__ x) {
  size_t i = ((size_t)blockIdx.x * 256 + threadIdx.x) * 4;
  const size_t S = (size_t)BB * NN * FF;
  f32x4_t a = *(const f32x4_t*)&part[i];
  f32x4_t b = *(const f32x4_t*)&part[S + i];
  f32x4_t c = *(const f32x4_t*)&part[2 * S + i];
  f32x4_t d = *(const f32x4_t*)&part[3 * S + i];
  f32x4_t r = (a + b) + (c + d);
  *(f32x4_t*)&x[i] = r;
}

// ---------------- fused msg step (512 thr, LDS edge staging, reg-staged dbuf) ----------------
__global__ __launch_bounds__(512) void k_msg2(const float* __restrict__ x_in,
    float* __restrict__ x_out, const float* __restrict__ sposW,
    const int* __restrict__ coff, const int* __restrict__ csrc,
    const float* __restrict__ csw, const unsigned short* __restrict__ WTgh,
    const unsigned short* __restrict__ WTgl, const float* __restrict__ lng,
    const float* __restrict__ lnb, int last,
    unsigned short* __restrict__ xTh, unsigned short* __restrict__ xTl) {
  __shared__ unsigned Ah[32][132];
  __shared__ unsigned Al[32][132];
  __shared__ unsigned short Bh[2][8192];
  __shared__ unsigned short Bl[2][8192];
  __shared__ float redS[32][8];
  __shared__ float redQ[32][8];
  __shared__ int sed[EMAX];
  __shared__ float wed[EMAX];
  int tid = threadIdx.x;
  // XCD-aware: batch b pinned to one XCD so x(b) stays in its L2
  int id = blockIdx.x;
  int b = id & 7;
  int nb = id >> 3;
  int n0 = nb * 32;
  int wv = tid >> 6, L = tid & 63, lhi = L >> 4, llo = L & 15;

  u32x4_t rbh[2], rbl[2];
  auto loadB = [&](int kc) {
    const u32x4_t* sh = (const u32x4_t*)(WTgh + (size_t)kc * 8192);
    const u32x4_t* sl = (const u32x4_t*)(WTgl + (size_t)kc * 8192);
    #pragma unroll
    for (int i = 0; i < 2; i++) { rbh[i] = sh[tid + i * 512]; rbl[i] = sl[tid + i * 512]; }
  };
  auto writeB = [&](int buf) {
    u32x4_t* dh = (u32x4_t*)Bh[buf];
    u32x4_t* dl = (u32x4_t*)Bl[buf];
    #pragma unroll
    for (int i = 0; i < 2; i++) {
      int es = swz16(tid + i * 512);
      dh[es] = rbh[i]; dl[es] = rbl[i];
    }
  };

  loadB(0);   // in flight during edge staging + gather

  // stage this block's CSR records into LDS (coalesced)
  int e0b = coff[n0];
  int ecnt = coff[n0 + 32] - e0b;
  for (int i = tid; i < ecnt && i < EMAX; i += 512) {
    sed[i] = csrc[e0b + i];
    wed[i] = csw[e0b + i];
  }
  __syncthreads();

  // gather phase: 16 threads per row, 16 features each; per-feature edge order unchanged
  {
    int row = tid >> 4, seg = tid & 15;
    int n = n0 + row;
    float g[16];
    #pragma unroll
    for (int i = 0; i < 16; i++) g[i] = 0.f;
    int e0 = coff[n] - e0b, e1 = coff[n + 1] - e0b;
    for (int e = e0; e < e1; e++) {
      int s; float w;
      if (e < EMAX) { s = sed[e]; w = wed[e]; }
      else { s = csrc[e0b + e]; w = csw[e0b + e]; }
      const f32x4_t* px = (const f32x4_t*)(x_in + ((size_t)b * NN + s) * FF + seg * 16);
      #pragma unroll
      for (int i = 0; i < 4; i++) {
        f32x4_t v = px[i];
        g[4*i]   += w * v[0]; g[4*i+1] += w * v[1];
        g[4*i+2] += w * v[2]; g[4*i+3] += w * v[3];
      }
    }
    #pragma unroll
    for (int i = 0; i < 8; i++) {
      unsigned h, l;
      split_pk(g[2 * i], g[2 * i + 1], h, l);
      Ah[row][seg * 8 + i] = h;
      Al[row][seg * 8 + i] = l;
    }
  }
  writeB(0);

  // preload residual + sposW sums (hidden under GEMM loop)
  f32x4_t szr[2][2];
  #pragma unroll
  for (int rb = 0; rb < 2; rb++)
    #pragma unroll
    for (int cb = 0; cb < 2; cb++) {
      int col = wv * 32 + cb * 16 + llo;
      #pragma unroll
      for (int r = 0; r < 4; r++) {
        int row = rb * 16 + lhi * 4 + r;
        szr[rb][cb][r] = sposW[(size_t)(n0 + row) * FF + col]
                       + x_in[((size_t)b * NN + n0 + row) * FF + col];
      }
    }
  __syncthreads();

  f32x4_t acc[2][2];
  #pragma unroll
  for (int i = 0; i < 2; i++)
    #pragma unroll
    for (int j = 0; j < 2; j++) { f32x4_t t = {0.f, 0.f, 0.f, 0.f}; acc[i][j] = t; }

  for (int kc = 0; kc < 8; kc++) {
    int cur = kc & 1;
    if (kc < 7) loadB(kc + 1);          // loads in flight under MFMA
    u32x4_t a0h = *(const u32x4_t*)&Ah[llo][kc * 16 + lhi * 4];
    u32x4_t a0l = *(const u32x4_t*)&Al[llo][kc * 16 + lhi * 4];
    u32x4_t a1h = *(const u32x4_t*)&Ah[llo + 16][kc * 16 + lhi * 4];
    u32x4_t a1l = *(const u32x4_t*)&Al[llo + 16][kc * 16 + lhi * 4];
    #pragma unroll
    for (int cb = 0; cb < 2; cb++) {
      int off = swz16((wv * 32 + cb * 16 + llo) * 4 + lhi) * 8;
      u32x4_t bh = *(const u32x4_t*)&Bh[cur][off];
      u32x4_t bl = *(const u32x4_t*)&Bl[cur][off];
      acc[0][cb] = mfma16(a0h, bh, mfma16(a0h, bl, mfma16(a0l, bh, acc[0][cb])));
      acc[1][cb] = mfma16(a1h, bh, mfma16(a1h, bl, mfma16(a1l, bh, acc[1][cb])));
    }
    if (kc < 7) writeB(cur ^ 1);
    __syncthreads();
  }

  // epilogue: + (sposW + residual), then LayerNorm
  #pragma unroll
  for (int rb = 0; rb < 2; rb++)
    #pragma unroll
    for (int cb = 0; cb < 2; cb++) {
      #pragma unroll
      for (int r = 0; r < 4; r++) acc[rb][cb][r] += szr[rb][cb][r];
    }
  float ps[2][4], pq[2][4];
  #pragma unroll
  for (int rb = 0; rb < 2; rb++)
    #pragma unroll
    for (int r = 0; r < 4; r++) {
      float s = 0.f, q = 0.f;
      #pragma unroll
      for (int cb = 0; cb < 2; cb++) { float y = acc[rb][cb][r]; s += y; q += y * y; }
      #pragma unroll
      for (int m = 1; m < 16; m <<= 1) { s += __shfl_xor(s, m); q += __shfl_xor(q, m); }
      ps[rb][r] = s; pq[rb][r] = q;
    }
  if (llo == 0) {
    #pragma unroll
    for (int rb = 0; rb < 2; rb++)
      #pragma unroll
      for (int r = 0; r < 4; r++) {
        int row = rb * 16 + lhi * 4 + r;
        redS[row][wv] = ps[rb][r];
        redQ[row][wv] = pq[rb][r];
      }
  }
  __syncthreads();
  float mrs[2][4][2];
  #pragma unroll
  for (int rb = 0; rb < 2; rb++)
    #pragma unroll
    for (int r = 0; r < 4; r++) {
      int row = rb * 16 + lhi * 4 + r;
      float S = 0.f, Q = 0.f;
      #pragma unroll
      for (int wq = 0; wq < 8; wq++) { S += redS[row][wq]; Q += redQ[row][wq]; }
      float mean = S * (1.f / 256.f);
      float var = Q * (1.f / 256.f) - mean * mean;
      mrs[rb][r][0] = mean;
      mrs[rb][r][1] = rsqrtf(var + 1e-5f);
    }
  #pragma unroll
  for (int cb = 0; cb < 2; cb++) {
    int col = wv * 32 + cb * 16 + llo;
    float gg = lng[col], bb = lnb[col];
    #pragma unroll
    for (int rb = 0; rb < 2; rb++)
      #pragma unroll
      for (int r = 0; r < 4; r++) {
        int row = rb * 16 + lhi * 4 + r;
        float o = (acc[rb][cb][r] - mrs[rb][r][0]) * mrs[rb][r][1] * gg + bb;
        if (!last) {
          x_out[((size_t)b * NN + n0 + row) * FF + col] = o;
        } else {
          size_t idx = (((size_t)b * 32 + nb) * 256 + col) * 32 + row;
          unsigned short hh = f2bf(o);
          xTh[idx] = hh;
          xTl[idx] = f2bf(o - ashf(hh));
        }
      }
  }
}

// ---------------- proj2 (64-row tile, single-buffer LDS + reg prefetch) ----------------
__global__ __launch_bounds__(256, 3) void k_proj2(const float* __restrict__ qxy,
    const float* __restrict__ mQ, const float* __restrict__ liQ,
    const float* __restrict__ npos, const unsigned short* __restrict__ xTh,
    const unsigned short* __restrict__ xTl, unsigned short* __restrict__ latTh,
    unsigned short* __restrict__ latTl) {
  __shared__ unsigned short BstH[8192];
  __shared__ unsigned short BstL[8192];
  __shared__ unsigned short AstH[2048];
  __shared__ unsigned short AstL[2048];
  __shared__ float nps[NN * 2];
  int tid = threadIdx.x;
  // XCD-aware: batch b pinned to one XCD so xT(b) stays in its L2
  int id = blockIdx.x;
  int b = id & 7;
  int q64 = id >> 3;             // 0..63 (64-row block)
  int q0 = q64 * 64;
  int wv = tid >> 6, L = tid & 63, lhi = L >> 4, llo = L & 15;
  int aq = tid >> 2, t3 = tid & 3, an8 = t3 * 8;
  int aoff = swz16(aq * 4 + t3) * 8;

  {
    const f32x4_t* s4 = (const f32x4_t*)npos;
    *(f32x4_t*)&nps[tid * 4] = s4[tid];
    *(f32x4_t*)&nps[(tid + 256) * 4] = s4[tid + 256];
  }
  int qg = b * NP + q0 + aq;
  float2 qv = ((const float2*)qxy)[qg];
  float qm = mQ[qg], qli = liQ[qg];
  __syncthreads();

  u32x4_t rbh[4], rbl[4], chv, clv;

  auto coordA = [&](int kc) {
    int nb = kc * 32 + an8;
    float c[8];
    #pragma unroll
    for (int j = 0; j < 8; j++) {
      float nx = nps[(nb + j) * 2], ny = nps[(nb + j) * 2 + 1];
      float dx = qv.x - nx, dy = qv.y - ny;
      c[j] = __expf(-(dx * dx + dy * dy) - qm) * qli;
    }
    unsigned h[4], l[4];
    #pragma unroll
    for (int j = 0; j < 4; j++) split_pk(c[2 * j], c[2 * j + 1], h[j], l[j]);
    u32x4_t th = {h[0], h[1], h[2], h[3]}; chv = th;
    u32x4_t tl = {l[0], l[1], l[2], l[3]}; clv = tl;
  };
  auto loadB = [&](int kc) {
    const u32x4_t* sh = (const u32x4_t*)(xTh + (size_t)(b * 32 + kc) * 8192);
    const u32x4_t* sl = (const u32x4_t*)(xTl + (size_t)(b * 32 + kc) * 8192);
    #pragma unroll
    for (int i = 0; i < 4; i++) { rbh[i] = sh[tid + i * 256]; rbl[i] = sl[tid + i * 256]; }
  };

  f32x4_t acc[4][4];
  #pragma unroll
  for (int i = 0; i < 4; i++)
    #pragma unroll
    for (int j = 0; j < 4; j++) { f32x4_t t = {0.f, 0.f, 0.f, 0.f}; acc[i][j] = t; }

  coordA(0);
  loadB(0);
  int aroff[4];
  #pragma unroll
  for (int rb = 0; rb < 4; rb++) aroff[rb] = swz16((llo + 16 * rb) * 4 + lhi) * 8;
  for (int kc = 0; kc < 32; kc++) {
    __syncthreads();
    #pragma unroll
    for (int i = 0; i < 4; i++) {
      int es = swz16(tid + i * 256);
      ((u32x4_t*)BstH)[es] = rbh[i];
      ((u32x4_t*)BstL)[es] = rbl[i];
    }
    *(u32x4_t*)&AstH[aoff] = chv;
    *(u32x4_t*)&AstL[aoff] = clv;
    __syncthreads();
    if (kc < 31) { loadB(kc + 1); coordA(kc + 1); }
    u32x4_t ah[4], al[4];
    #pragma unroll
    for (int rb = 0; rb < 4; rb++) {
      ah[rb] = *(const u32x4_t*)&AstH[aroff[rb]];
      al[rb] = *(const u32x4_t*)&AstL[aroff[rb]];
    }
    #pragma unroll
    for (int cb = 0; cb < 4; cb++) {
      int off = swz16((wv * 64 + cb * 16 + llo) * 4 + lhi) * 8;
      u32x4_t bh = *(const u32x4_t*)&BstH[off];
      u32x4_t bl = *(const u32x4_t*)&BstL[off];
      #pragma unroll
      for (int rb = 0; rb < 4; rb++)
        acc[rb][cb] = mfma16(ah[rb], bh, mfma16(ah[rb], bl, mfma16(al[rb], bh, acc[rb][cb])));
    }
  }
  #pragma unroll
  for (int rb = 0; rb < 4; rb++)
    #pragma unroll
    for (int cb = 0; cb < 4; cb++) {
      int col = wv * 64 + cb * 16 + llo;
      int fc = col >> 5, kk = col & 31;
      f32x4_t v = acc[rb][cb];
      #pragma unroll
      for (int r = 0; r < 4; r++) {
        int row = rb * 16 + lhi * 4 + r;                 // 0..63
        int bt = b * 128 + q64 * 2 + (row >> 5);
        size_t idx = ((size_t)bt * 8 + fc) * 1024 + (row & 31) * 32 + kk;
        unsigned short hh = f2bf(v[r]);
        latTh[idx] = hh;
        latTl[idx] = f2bf(v[r] - ashf(hh));
      }
    }
}

// ---------------- decoder (single-buffer LDS + reg prefetch) ----------------
__global__ __launch_bounds__(256, 4) void k_decoder(const unsigned short* __restrict__ latTh,
    const unsigned short* __restrict__ latTl, const float* __restrict__ qxy,
    const unsigned short* __restrict__ WTd1h, const unsigned short* __restrict__ WTd1l,
    const float* __restrict__ bd1, const float* __restrict__ Wd1,
    const float* __restrict__ Wd2, const float* __restrict__ bd2, float* __restrict__ out) {
  __shared__ unsigned short BstH[8192];
  __shared__ unsigned short BstL[8192];
  __shared__ unsigned short AstH[1024];
  __shared__ unsigned short AstL[1024];
  __shared__ float qs[32][2];
  __shared__ float red[4][32][3];
  int tid = threadIdx.x;
  int bt = blockIdx.x;
  int wv = tid >> 6, L = tid & 63, lhi = L >> 4, llo = L & 15;

  u32x4_t rbh[4], rbl[4], ra;
  auto loadB = [&](int kc) {
    const u32x4_t* sh = (const u32x4_t*)(WTd1h + (size_t)kc * 8192);
    const u32x4_t* sl = (const u32x4_t*)(WTd1l + (size_t)kc * 8192);
    #pragma unroll
    for (int i = 0; i < 4; i++) { rbh[i] = sh[tid + i * 256]; rbl[i] = sl[tid + i * 256]; }
  };
  auto loadA = [&](int kc) {
    if (tid < 128)
      ra = ((const u32x4_t*)(latTh + ((size_t)bt * 8 + kc) * 1024))[tid];
    else
      ra = ((const u32x4_t*)(latTl + ((size_t)bt * 8 + kc) * 1024))[tid - 128];
  };

  if (tid < 64) qs[tid >> 1][tid & 1] = qxy[((size_t)bt * 32 + (tid >> 1)) * 2 + (tid & 1)];
  loadB(0); loadA(0);
  __syncthreads();

  f32x4_t acc[2][4];
  #pragma unroll
  for (int cb = 0; cb < 4; cb++) {
    int col = wv * 64 + cb * 16 + llo;
    float wa = Wd1[256 * FF + col], wb = Wd1[257 * FF + col], bc = bd1[col];
    #pragma unroll
    for (int rb = 0; rb < 2; rb++) {
      f32x4_t t;
      #pragma unroll
      for (int r = 0; r < 4; r++) {
        int row = rb * 16 + lhi * 4 + r;
        t[r] = bc + qs[row][0] * wa + qs[row][1] * wb;
      }
      acc[rb][cb] = t;
    }
  }

  int a0off = swz16(llo * 4 + lhi) * 8;
  int a1off = swz16((llo + 16) * 4 + lhi) * 8;
  for (int kc = 0; kc < 8; kc++) {
    __syncthreads();
    #pragma unroll
    for (int i = 0; i < 4; i++) {
      int es = swz16(tid + i * 256);
      ((u32x4_t*)BstH)[es] = rbh[i];
      ((u32x4_t*)BstL)[es] = rbl[i];
    }
    if (tid < 128) ((u32x4_t*)AstH)[swz16(tid)] = ra;
    else ((u32x4_t*)AstL)[swz16(tid - 128)] = ra;
    __syncthreads();
    if (kc < 7) { loadB(kc + 1); loadA(kc + 1); }
    u32x4_t a0h = *(const u32x4_t*)&AstH[a0off];
    u32x4_t a0l = *(const u32x4_t*)&AstL[a0off];
    u32x4_t a1h = *(const u32x4_t*)&AstH[a1off];
    u32x4_t a1l = *(const u32x4_t*)&AstL[a1off];
    #pragma unroll
    for (int cb = 0; cb < 4; cb++) {
      int off = swz16((wv * 64 + cb * 16 + llo) * 4 + lhi) * 8;
      u32x4_t bh = *(const u32x4_t*)&BstH[off];
      u32x4_t bl = *(const u32x4_t*)&BstL[off];
      acc[0][cb] = mfma16(a0h, bh, mfma16(a0h, bl, mfma16(a0l, bh, acc[0][cb])));
      acc[1][cb] = mfma16(a1h, bh, mfma16(a1h, bl, mfma16(a1l, bh, acc[1][cb])));
    }
  }

  float po[2][4][3];
  #pragma unroll
  for (int rb = 0; rb < 2; rb++)
    #pragma unroll
    for (int r = 0; r < 4; r++) { po[rb][r][0] = 0.f; po[rb][r][1] = 0.f; po[rb][r][2] = 0.f; }
  #pragma unroll
  for (int rb = 0; rb < 2; rb++)
    #pragma unroll
    for (int cb = 0; cb < 4; cb++) {
      int col = wv * 64 + cb * 16 + llo;
      float w0 = Wd2[col * 3], w1 = Wd2[col * 3 + 1], w2 = Wd2[col * 3 + 2];
      f32x4_t v = acc[rb][cb];
      #pragma unroll
      for (int r = 0; r < 4; r++) {
        float hv = fmaxf(v[r], 0.f);
        po[rb][r][0] += hv * w0; po[rb][r][1] += hv * w1; po[rb][r][2] += hv * w2;
      }
    }
  #pragma unroll
  for (int o = 8; o; o >>= 1)
    #pragma unroll
    for (int rb = 0; rb < 2; rb++)
      #pragma unroll
      for (int r = 0; r < 4; r++) {
        po[rb][r][0] += __shfl_xor(po[rb][r][0], o);
        po[rb][r][1] += __shfl_xor(po[rb][r][1], o);
        po[rb][r][2] += __shfl_xor(po[rb][r][2], o);
      }
  if (llo == 0) {
    #pragma unroll
    for (int rb = 0; rb < 2; rb++)
      #pragma unroll
      for (int r = 0; r < 4; r++) {
        int row = rb * 16 + lhi * 4 + r;
        red[wv][row][0] = po[rb][r][0];
        red[wv][row][1] = po[rb][r][1];
        red[wv][row][2] = po[rb][r][2];
      }
  }
  __syncthreads();
  if (tid < 96) {
    int row = tid / 3, o = tid % 3;
    float s = red[0][row][o] + red[1][row][o] + red[2][row][o] + red[3][row][o] + bd2[o];
    out[((size_t)bt * 32 + row) * 3 + o] = s;
  }
}

extern "C" void kernel_launch(void* const* d_in, const int* in_sizes, int n_in,
                              void* d_out, int out_size, void* d_ws, size_t ws_size,
                              hipStream_t stream) {
  const float* inx = (const float*)d_in[0];
  const float* iny = (const float*)d_in[1];
  const float* qxy = (const float*)d_in[2];
  const float* npos = (const float*)d_in[3];
  const float* We1 = (const float*)d_in[4];
  const float* be1 = (const float*)d_in[5];
  const float* We2 = (const float*)d_in[6];
  const float* be2 = (const float*)d_in[7];
  const float* Wg  = (const float*)d_in[8];
  const float* bg  = (const float*)d_in[9];
  const float* lng = (const float*)d_in[10];
  const float* lnb = (const float*)d_in[11];
  const float* Wd1 = (const float*)d_in[12];
  const float* bd1 = (const float*)d_in[13];
  const float* Wd2 = (const float*)d_in[14];
  const float* bd2 = (const float*)d_in[15];
  const int* eidx  = (const int*)d_in[16];
  float* out = (float*)d_out;

  char* w = (char*)d_ws;
  auto carve = [&](size_t n) { char* p = w; w += (n + 255) & ~(size_t)255; return p; };
  char* encR = carve((size_t)2 * BB * NP * FF * 2);                          // 32 MB
  unsigned short* encTh = (unsigned short*)encR;
  unsigned short* encTl = (unsigned short*)(encR + (size_t)BB * NP * FF * 2);
  unsigned short* latTh = encTh;   // alias (dead after proj1)
  unsigned short* latTl = encTl;
  float* xA = (float*)carve((size_t)BB * NN * FF * 4);                       // 8 MB
  float* xB = (float*)carve((size_t)BB * NN * FF * 4);                       // 8 MB
  unsigned short* xTh = (unsigned short*)carve((size_t)BB * NN * FF * 2);    // 4 MB
  unsigned short* xTl = (unsigned short*)carve((size_t)BB * NN * FF * 2);    // 4 MB
  float* part = (float*)carve((size_t)4 * BB * NN * FF * 4);                 // 32 MB
  float* mI   = (float*)carve((size_t)BB * NP * 4);
  float* liI  = (float*)carve((size_t)BB * NP * 4);
  float* mQ   = (float*)carve((size_t)BB * NP * 4);
  float* liQ  = (float*)carve((size_t)BB * NP * 4);
  unsigned short* WTe2h = (unsigned short*)carve((size_t)8 * 256 * 32 * 2);
  unsigned short* WTe2l = (unsigned short*)carve((size_t)8 * 256 * 32 * 2);
  unsigned short* WTgh  = (unsigned short*)carve((size_t)8 * 256 * 32 * 2);
  unsigned short* WTgl  = (unsigned short*)carve((size_t)8 * 256 * 32 * 2);
  unsigned short* WTd1h = (unsigned short*)carve((size_t)8 * 256 * 32 * 2);
  unsigned short* WTd1l = (unsigned short*)carve((size_t)8 * 256 * 32 * 2);
  float* sposW = (float*)carve((size_t)NN * FF * 4);
  float* dinv = (float*)carve(NN * 4);
  float* csw  = (float*)carve((NE + NN) * 4);
  int* coff   = (int*)carve((NN + 1) * 4);
  int* csrc   = (int*)carve((NE + NN) * 4);
  int* cntg   = (int*)carve((size_t)NSEG * NN * 4);

  const int* esrc = eidx;
  const int* edst = eidx + NE;

  k_cnt<<<dim3(NSEG), dim3(1024), 0, stream>>>(edst, cntg);
  k_scan2<<<dim3(1), dim3(1024), 0, stream>>>(cntg, dinv, coff);
  k_fill2<<<dim3(NSEG + 1), dim3(1024), 0, stream>>>(esrc, edst, dinv, coff, cntg, csrc, csw);
  k_posb<<<dim3(NN), dim3(256), 0, stream>>>(npos, coff, csrc, csw, Wg, bg, sposW);
  k_pack_w<<<dim3(8, 3), dim3(256), 0, stream>>>(We2, Wg, Wd1, WTe2h, WTe2l, WTgh, WTgl,
                                                 WTd1h, WTd1l);

  k_stats<<<dim3(BB * NP / 4, 2), dim3(256), 0, stream>>>(inx, qxy, npos, mI, liI, mQ, liQ);
  k_encoder<<<dim3(BB * NP / 32), dim3(256), 0, stream>>>(inx, iny, We1, be1, WTe2h, WTe2l, be2,
                                                          encTh, encTl);
  k_proj1<<<dim3(1024), dim3(256), 0, stream>>>(inx, mI, liI, npos, encTh, encTl, part);
  k_reduce<<<dim3(BB * NN * FF / 1024), dim3(256), 0, stream>>>(part, xA);
  for (int s = 0; s < NSTEP; s++) {
    const float* xi = (s & 1) ? xB : xA;
    float* xo = (s & 1) ? xA : xB;
    k_msg2<<<dim3(256), dim3(512), 0, stream>>>(xi, xo, sposW, coff, csrc, csw,
                                                WTgh, WTgl, lng, lnb,
                                                (s == NSTEP - 1) ? 1 : 0, xTh, xTl);
  }
  k_proj2<<<dim3(512), dim3(256), 0, stream>>>(qxy, mQ, liQ, npos, xTh, xTl, latTh, latTl);
  k_decoder<<<dim3(BB * NP / 32), dim3(256), 0, stream>>>(latTh, latTl, qxy, WTd1h, WTd1l,
                                                          bd1, Wd1, Wd2, bd2, out);
}

// Round 17
// 531.775 us; speedup vs baseline: 1.3070x; 1.0013x over previous
//
#include <hip/hip_runtime.h>

#define BB 8
#define NP 4096    // NPTS == NQ
#define NN 1024
#define NE 8192
#define FF 256
#define TS 264
#define NSTEP 16
#define NSEG 64
#define SEGSZ 128  // NSEG*SEGSZ == NE
#define EMAX 1536  // per-block staged CSR records (mean ~288)

typedef float f32x4_t __attribute__((ext_vector_type(4)));
typedef __bf16 bf16x8_t __attribute__((ext_vector_type(8)));
typedef unsigned int u32x4_t __attribute__((ext_vector_type(4)));
typedef unsigned int u32x2_t __attribute__((ext_vector_type(2)));

// hardware RNE f32->bf16; bit-identical to SW round-to-nearest-even on normals
static __device__ __forceinline__ unsigned short f2bf(float f) {
  return __builtin_bit_cast(unsigned short, static_cast<__bf16>(f));
}
static __device__ __forceinline__ float ashf(unsigned short s) {
  union { unsigned u; float f; } t; t.u = (unsigned)s << 16; return t.f;
}
// split a,b into hi/lo bf16 pairs packed as u32
static __device__ __forceinline__ void split_pk(float a, float b, unsigned& h, unsigned& l) {
  unsigned short ha = f2bf(a), hb = f2bf(b);
  unsigned short la = f2bf(a - ashf(ha)), lb = f2bf(b - ashf(hb));
  h = (unsigned)ha | ((unsigned)hb << 16);
  l = (unsigned)la | ((unsigned)lb << 16);
}
static __device__ __forceinline__ f32x4_t mfma16(u32x4_t a, u32x4_t b, f32x4_t c) {
  return __builtin_amdgcn_mfma_f32_16x16x32_bf16(
      __builtin_bit_cast(bf16x8_t, a), __builtin_bit_cast(bf16x8_t, b), c, 0, 0, 0);
}
// 16B-entry XOR swizzle: spreads 64-byte fragment rows over all 32 LDS banks
static __device__ __forceinline__ int swz16(int e) { return e ^ ((e >> 3) & 7); }

// ---------------- graph preprocessing (segmented, deterministic) ----------------
__global__ __launch_bounds__(1024) void k_cnt(const int* __restrict__ dstA,
                                              int* __restrict__ cntg) {
  __shared__ int ds[SEGSZ];
  int seg = blockIdx.x, n = threadIdx.x;
  if (n < SEGSZ) ds[n] = dstA[seg * SEGSZ + n];
  __syncthreads();
  int c = 0;
  #pragma unroll 8
  for (int e = 0; e < SEGSZ; e++) c += (ds[e] == n) ? 1 : 0;
  cntg[seg * NN + n] = c;
}

__global__ __launch_bounds__(1024) void k_scan2(const int* __restrict__ cntg,
    float* __restrict__ dinv, int* __restrict__ csr_off) {
  __shared__ int s[NN];
  int n = threadIdx.x;
  int c = 1;
  for (int sg = 0; sg < NSEG; sg++) c += cntg[sg * NN + n];
  dinv[n] = rsqrtf((float)c);
  s[n] = c;
  __syncthreads();
  for (int st = 1; st < NN; st <<= 1) {
    int v = (n >= st) ? s[n - st] : 0;
    __syncthreads();
    s[n] += v;
    __syncthreads();
  }
  csr_off[n] = s[n] - c;
  if (n == NN - 1) csr_off[NN] = s[n];
}

__global__ __launch_bounds__(1024) void k_fill2(const int* __restrict__ srcA,
    const int* __restrict__ dstA, const float* __restrict__ dinv,
    const int* __restrict__ csr_off, const int* __restrict__ cntg,
    int* __restrict__ csr_src, float* __restrict__ csr_w) {
  int n = threadIdx.x;
  if (blockIdx.x == NSEG) {
    int pos = csr_off[n + 1] - 1;               // self loop last
    csr_src[pos] = n;
    csr_w[pos] = dinv[n] * dinv[n];
    return;
  }
  __shared__ int ds[SEGSZ], ss[SEGSZ];
  int seg = blockIdx.x;
  if (n < SEGSZ) { ds[n] = dstA[seg * SEGSZ + n]; ss[n] = srcA[seg * SEGSZ + n]; }
  __syncthreads();
  int base = csr_off[n];
  for (int s2 = 0; s2 < seg; s2++) base += cntg[s2 * NN + n];
  float dn = dinv[n];
  for (int e = 0; e < SEGSZ; e++) {
    if (ds[e] == n) {
      int sv = ss[e];
      csr_src[base] = sv;
      csr_w[base] = dinv[sv] * dn;
      base++;
    }
  }
}

// spos + sposW fused: one block per node n; spos sum recomputed redundantly per thread
__global__ __launch_bounds__(256) void k_posb(const float* __restrict__ npos,
    const int* __restrict__ csr_off, const int* __restrict__ csr_src,
    const float* __restrict__ csr_w, const float* __restrict__ Wg,
    const float* __restrict__ bg, float* __restrict__ sposW) {
  int n = blockIdx.x, f = threadIdx.x;
  float sx = 0.f, sy = 0.f;
  int e1 = csr_off[n + 1];
  for (int e = csr_off[n]; e < e1; e++) {
    float w = csr_w[e]; int s = csr_src[e];
    sx += w * npos[2 * s]; sy += w * npos[2 * s + 1];
  }
  sposW[(size_t)n * FF + f] = sx * Wg[f] + sy * Wg[FF + f] + bg[f];
}

// ---------------- softmax stats (inputs and queries in one launch) ----------------
__global__ __launch_bounds__(256) void k_stats(const float* __restrict__ inx,
    const float* __restrict__ qxy, const float* __restrict__ npos,
    float* __restrict__ mI, float* __restrict__ liI,
    float* __restrict__ mQ, float* __restrict__ liQ) {
  const float* xy = blockIdx.y ? qxy : inx;
  float* mOut = blockIdx.y ? mQ : mI;
  float* liOut = blockIdx.y ? liQ : liI;
  int wv = threadIdx.x >> 6, lane = threadIdx.x & 63;
  int pt = blockIdx.x * 4 + wv;
  float px = xy[pt * 2], py = xy[pt * 2 + 1];
  float s[16];
  float m = -1e30f;
  #pragma unroll
  for (int k = 0; k < 16; k++) {
    int n = lane + 64 * k;
    float2 np = ((const float2*)npos)[n];
    float dx = px - np.x, dy = py - np.y;
    float v = -(dx * dx + dy * dy);
    s[k] = v; m = fmaxf(m, v);
  }
  #pragma unroll
  for (int o = 32; o; o >>= 1) m = fmaxf(m, __shfl_xor(m, o));
  float l = 0.f;
  #pragma unroll
  for (int k = 0; k < 16; k++) l += __expf(s[k] - m);
  #pragma unroll
  for (int o = 32; o; o >>= 1) l += __shfl_xor(l, o);
  if (lane == 0) { mOut[pt] = m; liOut[pt] = 1.0f / l; }
}

// ---------------- weight prepack: WT[kc][n][kk] bf16 hi+lo ----------------
__global__ __launch_bounds__(256) void k_pack_w(const float* __restrict__ We2,
    const float* __restrict__ Wg, const float* __restrict__ Wd1,
    unsigned short* __restrict__ WTe2h, unsigned short* __restrict__ WTe2l,
    unsigned short* __restrict__ WTgh, unsigned short* __restrict__ WTgl,
    unsigned short* __restrict__ WTd1h, unsigned short* __restrict__ WTd1l) {
  int kc = blockIdx.x, which = blockIdx.y, n = threadIdx.x;
  const float* W = (which == 0) ? We2 : (which == 1) ? (Wg + 2 * FF) : Wd1;
  unsigned short* Dh = (which == 0) ? WTe2h : (which == 1) ? WTgh : WTd1h;
  unsigned short* Dl = (which == 0) ? WTe2l : (which == 1) ? WTgl : WTd1l;
  unsigned hu[16], lu[16];
  #pragma unroll
  for (int i = 0; i < 16; i++) {
    float a = W[(kc * 32 + 2 * i) * FF + n];
    float b = W[(kc * 32 + 2 * i + 1) * FF + n];
    split_pk(a, b, hu[i], lu[i]);
  }
  u32x4_t* dvh = (u32x4_t*)(Dh + ((size_t)kc * 256 + n) * 32);
  u32x4_t* dvl = (u32x4_t*)(Dl + ((size_t)kc * 256 + n) * 32);
  #pragma unroll
  for (int i = 0; i < 4; i++) {
    u32x4_t th = {hu[4 * i], hu[4 * i + 1], hu[4 * i + 2], hu[4 * i + 3]};
    u32x4_t tl = {lu[4 * i], lu[4 * i + 1], lu[4 * i + 2], lu[4 * i + 3]};
    dvh[i] = th; dvl[i] = tl;
  }
}

// ---------------- encoder: L1 fp32 VALU, L2 split-MFMA (reg-prefetch B); encT hi+lo ----------------
__global__ __launch_bounds__(256) void k_encoder(const float* __restrict__ inx,
    const float* __restrict__ iny, const float* __restrict__ We1,
    const float* __restrict__ be1, const unsigned short* __restrict__ WTe2h,
    const unsigned short* __restrict__ WTe2l, const float* __restrict__ be2,
    unsigned short* __restrict__ encTh, unsigned short* __restrict__ encTl) {
  __shared__ float xin[32][8];
  __shared__ float h[32][TS];
  __shared__ unsigned short Bh[8192];
  __shared__ unsigned short Bl[8192];
  int tid = threadIdx.x;
  int row0 = blockIdx.x * 32;
  int wv = tid >> 6, L = tid & 63, lhi = L >> 4, llo = L & 15;

  u32x4_t rbh[4], rbl[4];
  auto loadB = [&](int kc) {
    const u32x4_t* sh = (const u32x4_t*)(WTe2h + (size_t)kc * 8192);
    const u32x4_t* sl = (const u32x4_t*)(WTe2l + (size_t)kc * 8192);
    #pragma unroll
    for (int i = 0; i < 4; i++) { rbh[i] = sh[tid + i * 256]; rbl[i] = sl[tid + i * 256]; }
  };

  loadB(0);   // weight loads in flight under input staging + L1 compute

  if (tid < 160) {
    int pt = tid / 5, d = tid % 5;
    int r = row0 + pt;
    xin[pt][d] = (d < 2) ? inx[r * 2 + d] : iny[r * 3 + (d - 2)];
  }
  __syncthreads();
  {
    int f = tid;
    float w0 = We1[f], w1 = We1[256 + f], w2 = We1[512 + f], w3 = We1[768 + f], w4 = We1[1024 + f];
    float bb = be1[f];
    #pragma unroll 4
    for (int pt = 0; pt < 32; pt++) {
      float v = bb + xin[pt][0]*w0 + xin[pt][1]*w1 + xin[pt][2]*w2 + xin[pt][3]*w3 + xin[pt][4]*w4;
      h[pt][f] = fmaxf(v, 0.f);
    }
  }

  f32x4_t acc[2][4];
  #pragma unroll
  for (int cb = 0; cb < 4; cb++) {
    float bc = be2[wv * 64 + cb * 16 + llo];
    f32x4_t t = {bc, bc, bc, bc};
    acc[0][cb] = t; acc[1][cb] = t;
  }

  for (int kc = 0; kc < 8; kc++) {
    __syncthreads();                       // prev MFMA done reading B; (kc=0: h writes ordered)
    #pragma unroll
    for (int i = 0; i < 4; i++) {
      int es = swz16(tid + i * 256);
      ((u32x4_t*)Bh)[es] = rbh[i];
      ((u32x4_t*)Bl)[es] = rbl[i];
    }
    __syncthreads();
    if (kc < 7) loadB(kc + 1);             // next-kc weights in flight under repack + MFMA
    int kbase = kc * 32 + lhi * 8;
    u32x4_t a0h, a0l, a1h, a1l;
    {
      float p[8];
      *(f32x4_t*)p = *(const f32x4_t*)&h[llo][kbase];
      *(f32x4_t*)(p + 4) = *(const f32x4_t*)&h[llo][kbase + 4];
      unsigned hw[4], lw[4];
      #pragma unroll
      for (int i = 0; i < 4; i++) split_pk(p[2 * i], p[2 * i + 1], hw[i], lw[i]);
      u32x4_t th = {hw[0], hw[1], hw[2], hw[3]}; a0h = th;
      u32x4_t tl = {lw[0], lw[1], lw[2], lw[3]}; a0l = tl;
    }
    {
      float p[8];
      *(f32x4_t*)p = *(const f32x4_t*)&h[llo + 16][kbase];
      *(f32x4_t*)(p + 4) = *(const f32x4_t*)&h[llo + 16][kbase + 4];
      unsigned hw[4], lw[4];
      #pragma unroll
      for (int i = 0; i < 4; i++) split_pk(p[2 * i], p[2 * i + 1], hw[i], lw[i]);
      u32x4_t th = {hw[0], hw[1], hw[2], hw[3]}; a1h = th;
      u32x4_t tl = {lw[0], lw[1], lw[2], lw[3]}; a1l = tl;
    }
    #pragma unroll
    for (int cb = 0; cb < 4; cb++) {
      int col = wv * 64 + cb * 16 + llo;
      int off = swz16(col * 4 + lhi) * 8;
      u32x4_t bh = *(const u32x4_t*)&Bh[off];
      u32x4_t bl = *(const u32x4_t*)&Bl[off];
      acc[0][cb] = mfma16(a0h, bh, mfma16(a0h, bl, mfma16(a0l, bh, acc[0][cb])));
      acc[1][cb] = mfma16(a1h, bh, mfma16(a1h, bl, mfma16(a1l, bh, acc[1][cb])));
    }
  }
  #pragma unroll
  for (int rb = 0; rb < 2; rb++)
    #pragma unroll
    for (int cb = 0; cb < 4; cb++) {
      int col = wv * 64 + cb * 16 + llo;
      f32x4_t v = acc[rb][cb];
      size_t idx = ((size_t)blockIdx.x * 256 + col) * 32 + rb * 16 + lhi * 4;
      unsigned hw0, lw0, hw1, lw1;
      split_pk(v[0], v[1], hw0, lw0);
      split_pk(v[2], v[3], hw1, lw1);
      u32x2_t wh = {hw0, hw1}; *(u32x2_t*)&encTh[idx] = wh;
      u32x2_t wl = {lw0, lw1}; *(u32x2_t*)&encTl[idx] = wl;
    }
}

// ---------------- proj1 (split-K, 32-row tile, single-buffer LDS + reg prefetch) ----------------
__global__ __launch_bounds__(256, 4) void k_proj1(const float* __restrict__ inx,
    const float* __restrict__ mI, const float* __restrict__ liI,
    const float* __restrict__ npos, const unsigned short* __restrict__ encTh,
    const unsigned short* __restrict__ encTl, float* __restrict__ part) {
  __shared__ unsigned short BstH[8192];
  __shared__ unsigned short BstL[8192];
  __shared__ unsigned short AstH[1024];
  __shared__ unsigned short AstL[1024];
  int tid = threadIdx.x;
  // XCD-aware decode: each XCD owns 4 (b,z)-slices; 32 n-blocks per slice stay local
  int id = blockIdx.x;
  int xcd = id & 7, kid = id >> 3;
  int slice = xcd * 4 + (kid >> 5);
  int n0 = (kid & 31) * 32;
  int b = slice >> 2, z = slice & 3;
  int wv = tid >> 6, L = tid & 63, lhi = L >> 4, llo = L & 15;
  int an = tid >> 3, t7 = tid & 7, ap = t7 * 4;
  float2 npv = ((const float2*)npos)[n0 + an];
  int pbase0 = b * NP + z * 1024;
  int aoff = swz16(an * 4 + (t7 >> 1)) * 8 + (t7 & 1) * 4;

  u32x4_t rbh[4], rbl[4];
  unsigned ch0, ch1, cl0, cl1;

  auto coordA = [&](int kc) {
    int p = pbase0 + kc * 32 + ap;
    float c[4];
    #pragma unroll
    for (int j = 0; j < 4; j++) {
      float2 pxy = ((const float2*)inx)[p + j];
      float mm = mI[p + j], ll = liI[p + j];
      float dx = pxy.x - npv.x, dy = pxy.y - npv.y;
      c[j] = __expf(-(dx * dx + dy * dy) - mm) * ll;
    }
    split_pk(c[0], c[1], ch0, cl0);
    split_pk(c[2], c[3], ch1, cl1);
  };
  auto loadB = [&](int kc) {
    const u32x4_t* sh = (const u32x4_t*)(encTh + (size_t)(b * 128 + z * 32 + kc) * 8192);
    const u32x4_t* sl = (const u32x4_t*)(encTl + (size_t)(b * 128 + z * 32 + kc) * 8192);
    #pragma unroll
    for (int i = 0; i < 4; i++) { rbh[i] = sh[tid + i * 256]; rbl[i] = sl[tid + i * 256]; }
  };

  f32x4_t acc[2][4];
  #pragma unroll
  for (int i = 0; i < 2; i++)
    #pragma unroll
    for (int j = 0; j < 4; j++) { f32x4_t t = {0.f, 0.f, 0.f, 0.f}; acc[i][j] = t; }

  coordA(0);
  loadB(0);
  int a0off = swz16(llo * 4 + lhi) * 8;
  int a1off = swz16((llo + 16) * 4 + lhi) * 8;
  for (int kc = 0; kc < 32; kc++) {
    __syncthreads();                       // previous compute done reading LDS
    #pragma unroll
    for (int i = 0; i < 4; i++) {
      int es = swz16(tid + i * 256);
      ((u32x4_t*)BstH)[es] = rbh[i];
      ((u32x4_t*)BstL)[es] = rbl[i];
    }
    { u32x2_t wh = {ch0, ch1}; *(u32x2_t*)&AstH[aoff] = wh; }
    { u32x2_t wl = {cl0, cl1}; *(u32x2_t*)&AstL[aoff] = wl; }
    __syncthreads();
    if (kc < 31) { loadB(kc + 1); coordA(kc + 1); }   // in flight / co-issue during MFMA
    u32x4_t a0h = *(const u32x4_t*)&AstH[a0off];
    u32x4_t a0l = *(const u32x4_t*)&AstL[a0off];
    u32x4_t a1h = *(const u32x4_t*)&AstH[a1off];
    u32x4_t a1l = *(const u32x4_t*)&AstL[a1off];
    #pragma unroll
    for (int cb = 0; cb < 4; cb++) {
      int off = swz16((wv * 64 + cb * 16 + llo) * 4 + lhi) * 8;
      u32x4_t bh = *(const u32x4_t*)&BstH[off];
      u32x4_t bl = *(const u32x4_t*)&BstL[off];
      acc[0][cb] = mfma16(a0h, bh, mfma16(a0h, bl, mfma16(a0l, bh, acc[0][cb])));
      acc[1][cb] = mfma16(a1h, bh, mfma16(a1h, bl, mfma16(a1l, bh, acc[1][cb])));
    }
  }
  float* op = part + (((size_t)(z * BB + b)) * NN + n0) * FF;
  #pragma unroll
  for (int rb = 0; rb < 2; rb++)
    #pragma unroll
    for (int cb = 0; cb < 4; cb++) {
      int col = wv * 64 + cb * 16 + llo;
      f32x4_t v = acc[rb][cb];
      #pragma unroll
      for (int r = 0; r < 4; r++) op[(rb * 16 + lhi * 4 + r) * FF + col] = v[r];
    }
}

// reduce split-K parts -> x (fp32)
__global__ __launch_bounds__(256) void k_reduce(const float* __restrict__ part,
                                                float* __restrict__ x) {
  size_t i = ((size_t)blockIdx.x * 256 + threadIdx.x) * 4;
  const size_t S = (size_t)BB * NN * FF;
  f32x4_t a = *(const f32x4_t*)&part[i];
  f32x4_t b = *(const f32x4_t*)&part[S + i];
  f32x4_t c = *(const f32x4_t*)&part[2 * S + i];
  f32x4_t d = *(const f32x4_t*)&part[3 * S + i];
  f32x4_t r = (a + b) + (c + d);
  *(f32x4_t*)&x[i] = r;
}

// ---------------- fused msg step (512 thr, LDS edge staging, reg-staged dbuf) ----------------
__global__ __launch_bounds__(512) void k_msg2(const float* __restrict__ x_in,
    float* __restrict__ x_out, const float* __restrict__ sposW,
    const int* __restrict__ coff, const int* __restrict__ csrc,
    const float* __restrict__ csw, const unsigned short* __restrict__ WTgh,
    const unsigned short* __restrict__ WTgl, const float* __restrict__ lng,
    const float* __restrict__ lnb, int last,
    unsigned short* __restrict__ xTh, unsigned short* __restrict__ xTl) {
  __shared__ unsigned Ah[32][132];
  __shared__ unsigned Al[32][132];
  __shared__ unsigned short Bh[2][8192];
  __shared__ unsigned short Bl[2][8192];
  __shared__ float redS[32][8];
  __shared__ float redQ[32][8];
  __shared__ int sed[EMAX];
  __shared__ float wed[EMAX];
  int tid = threadIdx.x;
  // XCD-aware: batch b pinned to one XCD so x(b) stays in its L2
  int id = blockIdx.x;
  int b = id & 7;
  int nb = id >> 3;
  int n0 = nb * 32;
  int wv = tid >> 6, L = tid & 63, lhi = L >> 4, llo = L & 15;

  u32x4_t rbh[2], rbl[2];
  auto loadB = [&](int kc) {
    const u32x4_t* sh = (const u32x4_t*)(WTgh + (size_t)kc * 8192);
    const u32x4_t* sl = (const u32x4_t*)(WTgl + (size_t)kc * 8192);
    #pragma unroll
    for (int i = 0; i < 2; i++) { rbh[i] = sh[tid + i * 512]; rbl[i] = sl[tid + i * 512]; }
  };
  auto writeB = [&](int buf) {
    u32x4_t* dh = (u32x4_t*)Bh[buf];
    u32x4_t* dl = (u32x4_t*)Bl[buf];
    #pragma unroll
    for (int i = 0; i < 2; i++) {
      int es = swz16(tid + i * 512);
      dh[es] = rbh[i]; dl[es] = rbl[i];
    }
  };

  loadB(0);   // in flight during edge staging + gather

  // stage this block's CSR records into LDS (coalesced)
  int e0b = coff[n0];
  int ecnt = coff[n0 + 32] - e0b;
  for (int i = tid; i < ecnt && i < EMAX; i += 512) {
    sed[i] = csrc[e0b + i];
    wed[i] = csw[e0b + i];
  }
  __syncthreads();

  // gather phase: 16 threads per row, 16 features each; per-feature edge order unchanged
  {
    int row = tid >> 4, seg = tid & 15;
    int n = n0 + row;
    float g[16];
    #pragma unroll
    for (int i = 0; i < 16; i++) g[i] = 0.f;
    int e0 = coff[n] - e0b, e1 = coff[n + 1] - e0b;
    for (int e = e0; e < e1; e++) {
      int s; float w;
      if (e < EMAX) { s = sed[e]; w = wed[e]; }
      else { s = csrc[e0b + e]; w = csw[e0b + e]; }
      const f32x4_t* px = (const f32x4_t*)(x_in + ((size_t)b * NN + s) * FF + seg * 16);
      #pragma unroll
      for (int i = 0; i < 4; i++) {
        f32x4_t v = px[i];
        g[4*i]   += w * v[0]; g[4*i+1] += w * v[1];
        g[4*i+2] += w * v[2]; g[4*i+3] += w * v[3];
      }
    }
    #pragma unroll
    for (int i = 0; i < 8; i++) {
      unsigned h, l;
      split_pk(g[2 * i], g[2 * i + 1], h, l);
      Ah[row][seg * 8 + i] = h;
      Al[row][seg * 8 + i] = l;
    }
  }
  writeB(0);

  // preload residual + sposW sums (hidden under GEMM loop)
  f32x4_t szr[2][2];
  #pragma unroll
  for (int rb = 0; rb < 2; rb++)
    #pragma unroll
    for (int cb = 0; cb < 2; cb++) {
      int col = wv * 32 + cb * 16 + llo;
      #pragma unroll
      for (int r = 0; r < 4; r++) {
        int row = rb * 16 + lhi * 4 + r;
        szr[rb][cb][r] = sposW[(size_t)(n0 + row) * FF + col]
                       + x_in[((size_t)b * NN + n0 + row) * FF + col];
      }
    }
  __syncthreads();

  f32x4_t acc[2][2];
  #pragma unroll
  for (int i = 0; i < 2; i++)
    #pragma unroll
    for (int j = 0; j < 2; j++) { f32x4_t t = {0.f, 0.f, 0.f, 0.f}; acc[i][j] = t; }

  for (int kc = 0; kc < 8; kc++) {
    int cur = kc & 1;
    if (kc < 7) loadB(kc + 1);          // loads in flight under MFMA
    u32x4_t a0h = *(const u32x4_t*)&Ah[llo][kc * 16 + lhi * 4];
    u32x4_t a0l = *(const u32x4_t*)&Al[llo][kc * 16 + lhi * 4];
    u32x4_t a1h = *(const u32x4_t*)&Ah[llo + 16][kc * 16 + lhi * 4];
    u32x4_t a1l = *(const u32x4_t*)&Al[llo + 16][kc * 16 + lhi * 4];
    #pragma unroll
    for (int cb = 0; cb < 2; cb++) {
      int off = swz16((wv * 32 + cb * 16 + llo) * 4 + lhi) * 8;
      u32x4_t bh = *(const u32x4_t*)&Bh[cur][off];
      u32x4_t bl = *(const u32x4_t*)&Bl[cur][off];
      acc[0][cb] = mfma16(a0h, bh, mfma16(a0h, bl, mfma16(a0l, bh, acc[0][cb])));
      acc[1][cb] = mfma16(a1h, bh, mfma16(a1h, bl, mfma16(a1l, bh, acc[1][cb])));
    }
    if (kc < 7) writeB(cur ^ 1);
    __syncthreads();
  }

  // epilogue: + (sposW + residual), then LayerNorm
  #pragma unroll
  for (int rb = 0; rb < 2; rb++)
    #pragma unroll
    for (int cb = 0; cb < 2; cb++) {
      #pragma unroll
      for (int r = 0; r < 4; r++) acc[rb][cb][r] += szr[rb][cb][r];
    }
  float ps[2][4], pq[2][4];
  #pragma unroll
  for (int rb = 0; rb < 2; rb++)
    #pragma unroll
    for (int r = 0; r < 4; r++) {
      float s = 0.f, q = 0.f;
      #pragma unroll
      for (int cb = 0; cb < 2; cb++) { float y = acc[rb][cb][r]; s += y; q += y * y; }
      #pragma unroll
      for (int m = 1; m < 16; m <<= 1) { s += __shfl_xor(s, m); q += __shfl_xor(q, m); }
      ps[rb][r] = s; pq[rb][r] = q;
    }
  if (llo == 0) {
    #pragma unroll
    for (int rb = 0; rb < 2; rb++)
      #pragma unroll
      for (int r = 0; r < 4; r++) {
        int row = rb * 16 + lhi * 4 + r;
        redS[row][wv] = ps[rb][r];
        redQ[row][wv] = pq[rb][r];
      }
  }
  __syncthreads();
  float mrs[2][4][2];
  #pragma unroll
  for (int rb = 0; rb < 2; rb++)
    #pragma unroll
    for (int r = 0; r < 4; r++) {
      int row = rb * 16 + lhi * 4 + r;
      float S = 0.f, Q = 0.f;
      #pragma unroll
      for (int wq = 0; wq < 8; wq++) { S += redS[row][wq]; Q += redQ[row][wq]; }
      float mean = S * (1.f / 256.f);
      float var = Q * (1.f / 256.f) - mean * mean;
      mrs[rb][r][0] = mean;
      mrs[rb][r][1] = rsqrtf(var + 1e-5f);
    }
  #pragma unroll
  for (int cb = 0; cb < 2; cb++) {
    int col = wv * 32 + cb * 16 + llo;
    float gg = lng[col], bb = lnb[col];
    #pragma unroll
    for (int rb = 0; rb < 2; rb++)
      #pragma unroll
      for (int r = 0; r < 4; r++) {
        int row = rb * 16 + lhi * 4 + r;
        float o = (acc[rb][cb][r] - mrs[rb][r][0]) * mrs[rb][r][1] * gg + bb;
        if (!last) {
          x_out[((size_t)b * NN + n0 + row) * FF + col] = o;
        } else {
          size_t idx = (((size_t)b * 32 + nb) * 256 + col) * 32 + row;
          unsigned short hh = f2bf(o);
          xTh[idx] = hh;
          xTl[idx] = f2bf(o - ashf(hh));
        }
      }
  }
}

// ---------------- proj2 (64-row tile, single-buffer LDS + reg prefetch) ----------------
__global__ __launch_bounds__(256, 3) void k_proj2(const float* __restrict__ qxy,
    const float* __restrict__ mQ, const float* __restrict__ liQ,
    const float* __restrict__ npos, const unsigned short* __restrict__ xTh,
    const unsigned short* __restrict__ xTl, unsigned short* __restrict__ latTh,
    unsigned short* __restrict__ latTl) {
  __shared__ unsigned short BstH[8192];
  __shared__ unsigned short BstL[8192];
  __shared__ unsigned short AstH[2048];
  __shared__ unsigned short AstL[2048];
  __shared__ float nps[NN * 2];
  int tid = threadIdx.x;
  // XCD-aware: batch b pinned to one XCD so xT(b) stays in its L2
  int id = blockIdx.x;
  int b = id & 7;
  int q64 = id >> 3;             // 0..63 (64-row block)
  int q0 = q64 * 64;
  int wv = tid >> 6, L = tid & 63, lhi = L >> 4, llo = L & 15;
  int aq = tid >> 2, t3 = tid & 3, an8 = t3 * 8;
  int aoff = swz16(aq * 4 + t3) * 8;

  {
    const f32x4_t* s4 = (const f32x4_t*)npos;
    *(f32x4_t*)&nps[tid * 4] = s4[tid];
    *(f32x4_t*)&nps[(tid + 256) * 4] = s4[tid + 256];
  }
  int qg = b * NP + q0 + aq;
  float2 qv = ((const float2*)qxy)[qg];
  float qm = mQ[qg], qli = liQ[qg];
  __syncthreads();

  u32x4_t rbh[4], rbl[4], chv, clv;

  auto coordA = [&](int kc) {
    int nb = kc * 32 + an8;
    float c[8];
    #pragma unroll
    for (int j = 0; j < 8; j++) {
      float nx = nps[(nb + j) * 2], ny = nps[(nb + j) * 2 + 1];
      float dx = qv.x - nx, dy = qv.y - ny;
      c[j] = __expf(-(dx * dx + dy * dy) - qm) * qli;
    }
    unsigned h[4], l[4];
    #pragma unroll
    for (int j = 0; j < 4; j++) split_pk(c[2 * j], c[2 * j + 1], h[j], l[j]);
    u32x4_t th = {h[0], h[1], h[2], h[3]}; chv = th;
    u32x4_t tl = {l[0], l[1], l[2], l[3]}; clv = tl;
  };
  auto loadB = [&](int kc) {
    const u32x4_t* sh = (const u32x4_t*)(xTh + (size_t)(b * 32 + kc) * 8192);
    const u32x4_t* sl = (const u32x4_t*)(xTl + (size_t)(b * 32 + kc) * 8192);
    #pragma unroll
    for (int i = 0; i < 4; i++) { rbh[i] = sh[tid + i * 256]; rbl[i] = sl[tid + i * 256]; }
  };

  f32x4_t acc[4][4];
  #pragma unroll
  for (int i = 0; i < 4; i++)
    #pragma unroll
    for (int j = 0; j < 4; j++) { f32x4_t t = {0.f, 0.f, 0.f, 0.f}; acc[i][j] = t; }

  coordA(0);
  loadB(0);
  int aroff[4];
  #pragma unroll
  for (int rb = 0; rb < 4; rb++) aroff[rb] = swz16((llo + 16 * rb) * 4 + lhi) * 8;
  for (int kc = 0; kc < 32; kc++) {
    __syncthreads();
    #pragma unroll
    for (int i = 0; i < 4; i++) {
      int es = swz16(tid + i * 256);
      ((u32x4_t*)BstH)[es] = rbh[i];
      ((u32x4_t*)BstL)[es] = rbl[i];
    }
    *(u32x4_t*)&AstH[aoff] = chv;
    *(u32x4_t*)&AstL[aoff] = clv;
    __syncthreads();
    if (kc < 31) { loadB(kc + 1); coordA(kc + 1); }
    u32x4_t ah[4], al[4];
    #pragma unroll
    for (int rb = 0; rb < 4; rb++) {
      ah[rb] = *(const u32x4_t*)&AstH[aroff[rb]];
      al[rb] = *(const u32x4_t*)&AstL[aroff[rb]];
    }
    #pragma unroll
    for (int cb = 0; cb < 4; cb++) {
      int off = swz16((wv * 64 + cb * 16 + llo) * 4 + lhi) * 8;
      u32x4_t bh = *(const u32x4_t*)&BstH[off];
      u32x4_t bl = *(const u32x4_t*)&BstL[off];
      #pragma unroll
      for (int rb = 0; rb < 4; rb++)
        acc[rb][cb] = mfma16(ah[rb], bh, mfma16(ah[rb], bl, mfma16(al[rb], bh, acc[rb][cb])));
    }
  }
  #pragma unroll
  for (int rb = 0; rb < 4; rb++)
    #pragma unroll
    for (int cb = 0; cb < 4; cb++) {
      int col = wv * 64 + cb * 16 + llo;
      int fc = col >> 5, kk = col & 31;
      f32x4_t v = acc[rb][cb];
      #pragma unroll
      for (int r = 0; r < 4; r++) {
        int row = rb * 16 + lhi * 4 + r;                 // 0..63
        int bt = b * 128 + q64 * 2 + (row >> 5);
        size_t idx = ((size_t)bt * 8 + fc) * 1024 + (row & 31) * 32 + kk;
        unsigned short hh = f2bf(v[r]);
        latTh[idx] = hh;
        latTl[idx] = f2bf(v[r] - ashf(hh));
      }
    }
}

// ---------------- decoder (single-buffer LDS + reg prefetch) ----------------
__global__ __launch_bounds__(256, 4) void k_decoder(const unsigned short* __restrict__ latTh,
    const unsigned short* __restrict__ latTl, const float* __restrict__ qxy,
    const unsigned short* __restrict__ WTd1h, const unsigned short* __restrict__ WTd1l,
    const float* __restrict__ bd1, const float* __restrict__ Wd1,
    const float* __restrict__ Wd2, const float* __restrict__ bd2, float* __restrict__ out) {
  __shared__ unsigned short BstH[8192];
  __shared__ unsigned short BstL[8192];
  __shared__ unsigned short AstH[1024];
  __shared__ unsigned short AstL[1024];
  __shared__ float qs[32][2];
  __shared__ float red[4][32][3];
  int tid = threadIdx.x;
  int bt = blockIdx.x;
  int wv = tid >> 6, L = tid & 63, lhi = L >> 4, llo = L & 15;

  u32x4_t rbh[4], rbl[4], ra;
  auto loadB = [&](int kc) {
    const u32x4_t* sh = (const u32x4_t*)(WTd1h + (size_t)kc * 8192);
    const u32x4_t* sl = (const u32x4_t*)(WTd1l + (size_t)kc * 8192);
    #pragma unroll
    for (int i = 0; i < 4; i++) { rbh[i] = sh[tid + i * 256]; rbl[i] = sl[tid + i * 256]; }
  };
  auto loadA = [&](int kc) {
    if (tid < 128)
      ra = ((const u32x4_t*)(latTh + ((size_t)bt * 8 + kc) * 1024))[tid];
    else
      ra = ((const u32x4_t*)(latTl + ((size_t)bt * 8 + kc) * 1024))[tid - 128];
  };

  if (tid < 64) qs[tid >> 1][tid & 1] = qxy[((size_t)bt * 32 + (tid >> 1)) * 2 + (tid & 1)];
  loadB(0); loadA(0);
  __syncthreads();

  f32x4_t acc[2][4];
  #pragma unroll
  for (int cb = 0; cb < 4; cb++) {
    int col = wv * 64 + cb * 16 + llo;
    float wa = Wd1[256 * FF + col], wb = Wd1[257 * FF + col], bc = bd1[col];
    #pragma unroll
    for (int rb = 0; rb < 2; rb++) {
      f32x4_t t;
      #pragma unroll
      for (int r = 0; r < 4; r++) {
        int row = rb * 16 + lhi * 4 + r;
        t[r] = bc + qs[row][0] * wa + qs[row][1] * wb;
      }
      acc[rb][cb] = t;
    }
  }

  int a0off = swz16(llo * 4 + lhi) * 8;
  int a1off = swz16((llo + 16) * 4 + lhi) * 8;
  for (int kc = 0; kc < 8; kc++) {
    __syncthreads();
    #pragma unroll
    for (int i = 0; i < 4; i++) {
      int es = swz16(tid + i * 256);
      ((u32x4_t*)BstH)[es] = rbh[i];
      ((u32x4_t*)BstL)[es] = rbl[i];
    }
    if (tid < 128) ((u32x4_t*)AstH)[swz16(tid)] = ra;
    else ((u32x4_t*)AstL)[swz16(tid - 128)] = ra;
    __syncthreads();
    if (kc < 7) { loadB(kc + 1); loadA(kc + 1); }
    u32x4_t a0h = *(const u32x4_t*)&AstH[a0off];
    u32x4_t a0l = *(const u32x4_t*)&AstL[a0off];
    u32x4_t a1h = *(const u32x4_t*)&AstH[a1off];
    u32x4_t a1l = *(const u32x4_t*)&AstL[a1off];
    #pragma unroll
    for (int cb = 0; cb < 4; cb++) {
      int off = swz16((wv * 64 + cb * 16 + llo) * 4 + lhi) * 8;
      u32x4_t bh = *(const u32x4_t*)&BstH[off];
      u32x4_t bl = *(const u32x4_t*)&BstL[off];
      acc[0][cb] = mfma16(a0h, bh, mfma16(a0h, bl, mfma16(a0l, bh, acc[0][cb])));
      acc[1][cb] = mfma16(a1h, bh, mfma16(a1h, bl, mfma16(a1l, bh, acc[1][cb])));
    }
  }

  float po[2][4][3];
  #pragma unroll
  for (int rb = 0; rb < 2; rb++)
    #pragma unroll
    for (int r = 0; r < 4; r++) { po[rb][r][0] = 0.f; po[rb][r][1] = 0.f; po[rb][r][2] = 0.f; }
  #pragma unroll
  for (int rb = 0; rb < 2; rb++)
    #pragma unroll
    for (int cb = 0; cb < 4; cb++) {
      int col = wv * 64 + cb * 16 + llo;
      float w0 = Wd2[col * 3], w1 = Wd2[col * 3 + 1], w2 = Wd2[col * 3 + 2];
      f32x4_t v = acc[rb][cb];
      #pragma unroll
      for (int r = 0; r < 4; r++) {
        float hv = fmaxf(v[r], 0.f);
        po[rb][r][0] += hv * w0; po[rb][r][1] += hv * w1; po[rb][r][2] += hv * w2;
      }
    }
  #pragma unroll
  for (int o = 8; o; o >>= 1)
    #pragma unroll
    for (int rb = 0; rb < 2; rb++)
      #pragma unroll
      for (int r = 0; r < 4; r++) {
        po[rb][r][0] += __shfl_xor(po[rb][r][0], o);
        po[rb][r][1] += __shfl_xor(po[rb][r][1], o);
        po[rb][r][2] += __shfl_xor(po[rb][r][2], o);
      }
  if (llo == 0) {
    #pragma unroll
    for (int rb = 0; rb < 2; rb++)
      #pragma unroll
      for (int r = 0; r < 4; r++) {
        int row = rb * 16 + lhi * 4 + r;
        red[wv][row][0] = po[rb][r][0];
        red[wv][row][1] = po[rb][r][1];
        red[wv][row][2] = po[rb][r][2];
      }
  }
  __syncthreads();
  if (tid < 96) {
    int row = tid / 3, o = tid % 3;
    float s = red[0][row][o] + red[1][row][o] + red[2][row][o] + red[3][row][o] + bd2[o];
    out[((size_t)bt * 32 + row) * 3 + o] = s;
  }
}

extern "C" void kernel_launch(void* const* d_in, const int* in_sizes, int n_in,
                              void* d_out, int out_size, void* d_ws, size_t ws_size,
                              hipStream_t stream) {
  const float* inx = (const float*)d_in[0];
  const float* iny = (const float*)d_in[1];
  const float* qxy = (const float*)d_in[2];
  const float* npos = (const float*)d_in[3];
  const float* We1 = (const float*)d_in[4];
  const float* be1 = (const float*)d_in[5];
  const float* We2 = (const float*)d_in[6];
  const float* be2 = (const float*)d_in[7];
  const float* Wg  = (const float*)d_in[8];
  const float* bg  = (const float*)d_in[9];
  const float* lng = (const float*)d_in[10];
  const float* lnb = (const float*)d_in[11];
  const float* Wd1 = (const float*)d_in[12];
  const float* bd1 = (const float*)d_in[13];
  const float* Wd2 = (const float*)d_in[14];
  const float* bd2 = (const float*)d_in[15];
  const int* eidx  = (const int*)d_in[16];
  float* out = (float*)d_out;

  char* w = (char*)d_ws;
  auto carve = [&](size_t n) { char* p = w; w += (n + 255) & ~(size_t)255; return p; };
  char* encR = carve((size_t)2 * BB * NP * FF * 2);                          // 32 MB
  unsigned short* encTh = (unsigned short*)encR;
  unsigned short* encTl = (unsigned short*)(encR + (size_t)BB * NP * FF * 2);
  unsigned short* latTh = encTh;   // alias (dead after proj1)
  unsigned short* latTl = encTl;
  float* xA = (float*)carve((size_t)BB * NN * FF * 4);                       // 8 MB
  float* xB = (float*)carve((size_t)BB * NN * FF * 4);                       // 8 MB
  unsigned short* xTh = (unsigned short*)carve((size_t)BB * NN * FF * 2);    // 4 MB
  unsigned short* xTl = (unsigned short*)carve((size_t)BB * NN * FF * 2);    // 4 MB
  float* part = (float*)carve((size_t)4 * BB * NN * FF * 4);                 // 32 MB
  float* mI   = (float*)carve((size_t)BB * NP * 4);
  float* liI  = (float*)carve((size_t)BB * NP * 4);
  float* mQ   = (float*)carve((size_t)BB * NP * 4);
  float* liQ  = (float*)carve((size_t)BB * NP * 4);
  unsigned short* WTe2h = (unsigned short*)carve((size_t)8 * 256 * 32 * 2);
  unsigned short* WTe2l = (unsigned short*)carve((size_t)8 * 256 * 32 * 2);
  unsigned short* WTgh  = (unsigned short*)carve((size_t)8 * 256 * 32 * 2);
  unsigned short* WTgl  = (unsigned short*)carve((size_t)8 * 256 * 32 * 2);
  unsigned short* WTd1h = (unsigned short*)carve((size_t)8 * 256 * 32 * 2);
  unsigned short* WTd1l = (unsigned short*)carve((size_t)8 * 256 * 32 * 2);
  float* sposW = (float*)carve((size_t)NN * FF * 4);
  float* dinv = (float*)carve(NN * 4);
  float* csw  = (float*)carve((NE + NN) * 4);
  int* coff   = (int*)carve((NN + 1) * 4);
  int* csrc   = (int*)carve((NE + NN) * 4);
  int* cntg   = (int*)carve((size_t)NSEG * NN * 4);

  const int* esrc = eidx;
  const int* edst = eidx + NE;

  k_cnt<<<dim3(NSEG), dim3(1024), 0, stream>>>(edst, cntg);
  k_scan2<<<dim3(1), dim3(1024), 0, stream>>>(cntg, dinv, coff);
  k_fill2<<<dim3(NSEG + 1), dim3(1024), 0, stream>>>(esrc, edst, dinv, coff, cntg, csrc, csw);
  k_posb<<<dim3(NN), dim3(256), 0, stream>>>(npos, coff, csrc, csw, Wg, bg, sposW);
  k_pack_w<<<dim3(8, 3), dim3(256), 0, stream>>>(We2, Wg, Wd1, WTe2h, WTe2l, WTgh, WTgl,
                                                 WTd1h, WTd1l);

  k_stats<<<dim3(BB * NP / 4, 2), dim3(256), 0, stream>>>(inx, qxy, npos, mI, liI, mQ, liQ);
  k_encoder<<<dim3(BB * NP / 32), dim3(256), 0, stream>>>(inx, iny, We1, be1, WTe2h, WTe2l, be2,
                                                          encTh, encTl);
  k_proj1<<<dim3(1024), dim3(256), 0, stream>>>(inx, mI, liI, npos, encTh, encTl, part);
  k_reduce<<<dim3(BB * NN * FF / 1024), dim3(256), 0, stream>>>(part, xA);
  for (int s = 0; s < NSTEP; s++) {
    const float* xi = (s & 1) ? xB : xA;
    float* xo = (s & 1) ? xA : xB;
    k_msg2<<<dim3(256), dim3(512), 0, stream>>>(xi, xo, sposW, coff, csrc, csw,
                                                WTgh, WTgl, lng, lnb,
                                                (s == NSTEP - 1) ? 1 : 0, xTh, xTl);
  }
  k_proj2<<<dim3(512), dim3(256), 0, stream>>>(qxy, mQ, liQ, npos, xTh, xTl, latTh, latTl);
  k_decoder<<<dim3(BB * NP / 32), dim3(256), 0, stream>>>(latTh, latTl, qxy, WTd1h, WTd1l,
                                                          bd1, Wd1, Wd2, bd2, out);
}